// Round 4
// baseline (382.708 us; speedup 1.0000x reference)
//
#include <hip/hip_runtime.h>
#include <hip/hip_bf16.h>
#include <hip/hip_fp16.h>

// MultiHeadSparseAttention. R21 = R20 with latency-oriented ILP work in
// sparse_attn (counters show no saturated pipe at 45% occupancy):
//   - P2 processes its two rows INTERLEAVED: one batch of b128 reads, two
//     parallel scan chains, ONE zero+fence, both refines, ONE fence, both
//     scan2s, both exp passes, interleaved den reductions. Halves the
//     full-drain fences and doubles ILP on every serial chain.
//   - First KLOAD hoisted above the initial barrier (overlaps LDS zeroing).
//   - P3's first V-quad prefetched before P2 (global latency hidden under
//     P2's long VALU/DS phase).
//   - __launch_bounds__(512,4) pins VGPR<=128 so 4 waves/SIMD is kept.
// Numerics bit-identical to R20.
//   P1: wave w -> 16 s-tiles (s in [w*256, w*256+256))
//   P2: wave w -> rows 2w, 2w+1 (selection + exp, interleaved)
//   P3: wave w -> (d-block w&3, s-half w>>2); f32-atomic combine in Obuf
// L=S=2048, N=2, E=1024, H=16, D=64, k_sel = int(2048*sigmoid(0.3)) = 1176.
//
// ws (halfwords): Qf 4M | Kf 4M | Vt 4M | AOhi 4M | AOlo 4M | Whi 4M | Wlo 4M

#define KSEL 1176u
#define SROW 2048  // fp16 score row stride (elements) — bank-aligned rows
#define HSTR 132   // hist row stride in u32

typedef __attribute__((ext_vector_type(8))) short bf16x8;
typedef __attribute__((ext_vector_type(8))) _Float16 f16x8;
typedef __attribute__((ext_vector_type(4))) float f32x4;
typedef unsigned short ushort_t;

union S8 { bf16x8 v; ushort_t u[8]; };
union H8 { f16x8 v; ushort_t u[8]; };

#define MFMA16(A, B, C)  __builtin_amdgcn_mfma_f32_16x16x32_bf16(A, B, C, 0, 0, 0)
#define MFMAH16(A, B, C) __builtin_amdgcn_mfma_f32_16x16x32_f16(A, B, C, 0, 0, 0)

__device__ __forceinline__ ushort_t f2bf(float x) {  // RNE f32->bf16
  unsigned u = __float_as_uint(x);
  return (ushort_t)((u + 0x7FFFu + ((u >> 16) & 1u)) >> 16);
}
__device__ __forceinline__ float bf2f(ushort_t b) {
  return __uint_as_float(((unsigned)b) << 16);
}
__device__ __forceinline__ ushort_t f2h(float x) {
  return __half_as_ushort(__float2half(x));
}
__device__ __forceinline__ float h2f(ushort_t b) {
  return __half2float(__ushort_as_half(b));
}

// convert 8 fp32 (two float4) to fp16, store as f16x8
__device__ __forceinline__ void cvt8(ushort_t* dst, float4 p, float4 q) {
  H8 t;
  t.u[0] = f2h(p.x); t.u[1] = f2h(p.y); t.u[2] = f2h(p.z); t.u[3] = f2h(p.w);
  t.u[4] = f2h(q.x); t.u[5] = f2h(q.y); t.u[6] = f2h(q.z); t.u[7] = f2h(q.w);
  *(f16x8*)dst = t.v;
}

// ---- W prep: Wq/Wk/Wv -> fp16 (Whi only); Wo -> bf16 hi/lo PERMUTED ----
__global__ __launch_bounds__(256) void presplit_w(
    const float* __restrict__ W0, const float* __restrict__ W1,
    const float* __restrict__ W2, const float* __restrict__ W3,
    ushort_t* __restrict__ Whi, ushort_t* __restrict__ Wlo) {
  const int m = blockIdx.y;
  const float* W = (m == 0) ? W0 : (m == 1) ? W1 : (m == 2) ? W2 : W3;
  const size_t off = ((size_t)blockIdx.x * 256 + threadIdx.x) * 8;
  const size_t base = (size_t)m * 1048576 + off;
  if (m == 3) {
    const int f = (int)(off >> 10);
    const int r = (int)(off & 1023);
    const int hcol = r >> 6, d0 = r & 63;
    S8 hi_, lo_;
#pragma unroll
    for (int j = 0; j < 8; j++) {
      float x = W[(size_t)f * 1024 + (size_t)(d0 + j) * 16 + hcol];
      ushort_t hb = f2bf(x);
      hi_.u[j] = hb;
      lo_.u[j] = f2bf(x - bf2f(hb));
    }
    *(bf16x8*)&Whi[base] = hi_.v;
    *(bf16x8*)&Wlo[base] = lo_.v;
  } else {
    float4 p = *(const float4*)&W[off];
    float4 q = *(const float4*)&W[off + 4];
    cvt8(&Whi[base], p, q);
  }
}

// -------- fused Q/K/V projection: 64x128 tile, plain fp16, 1 MFMA --------
__global__ __launch_bounds__(256, 4) void proj_qkv(
    const float* __restrict__ Xq, const float* __restrict__ Xk,
    const float* __restrict__ Xv, const float* __restrict__ bq,
    const float* __restrict__ bk, const float* __restrict__ bv,
    const ushort_t* __restrict__ Whi, ushort_t* __restrict__ Qf,
    ushort_t* __restrict__ Kf, ushort_t* __restrict__ Vt) {
  __shared__ ushort_t Ah[64 * 72], Bh[128 * 72];
  const int z = blockIdx.z;
  const float* X = (z == 0) ? Xq : (z == 1) ? Xk : Xv;
  const float* bias = (z == 0) ? bq : (z == 1) ? bk : bv;
  const size_t zoff = (size_t)z * 1048576;

  const int tid = threadIdx.x;
  const int n0 = blockIdx.x * 128, m0 = blockIdx.y * 64;
  const int lane = tid & 63, wv = tid >> 6;
  const int lg = lane >> 4, lq = lane & 15;
  const int wr = wv >> 1, wc = wv & 1;
  const int sr = tid >> 2, c8 = (tid & 3) * 8;

  f32x4 acc[2][4] = {};

  const float* Xr = &X[(size_t)(m0 + sr) * 1024 + c8];
  const ushort_t* Bg0 = Whi + zoff + (size_t)(n0 + sr) * 1024 + c8;
  const ushort_t* Bg1 = Bg0 + 64 * 1024;

  float4 a0 = *(const float4*)&Xr[0],  a1 = *(const float4*)&Xr[4];
  float4 a2 = *(const float4*)&Xr[32], a3 = *(const float4*)&Xr[36];
  f16x8 pb0 = *(const f16x8*)&Bg0[0], pb1 = *(const f16x8*)&Bg0[32];
  f16x8 pb2 = *(const f16x8*)&Bg1[0], pb3 = *(const f16x8*)&Bg1[32];

  for (int k0 = 0; k0 < 1024; k0 += 64) {
    __syncthreads();
    cvt8(&Ah[sr * 72 + c8], a0, a1);
    cvt8(&Ah[sr * 72 + c8 + 32], a2, a3);
    *(f16x8*)&Bh[sr * 72 + c8] = pb0;
    *(f16x8*)&Bh[sr * 72 + c8 + 32] = pb1;
    *(f16x8*)&Bh[(64 + sr) * 72 + c8] = pb2;
    *(f16x8*)&Bh[(64 + sr) * 72 + c8 + 32] = pb3;
    if (k0 + 64 < 1024) {
      const float* Xn = Xr + k0 + 64;
      a0 = *(const float4*)&Xn[0];  a1 = *(const float4*)&Xn[4];
      a2 = *(const float4*)&Xn[32]; a3 = *(const float4*)&Xn[36];
      pb0 = *(const f16x8*)&Bg0[k0 + 64];
      pb1 = *(const f16x8*)&Bg0[k0 + 96];
      pb2 = *(const f16x8*)&Bg1[k0 + 64];
      pb3 = *(const f16x8*)&Bg1[k0 + 96];
    }
    __syncthreads();
#pragma unroll
    for (int kh = 0; kh < 2; kh++) {
      const int ko = kh * 32 + lg * 8;
      f16x8 bh0 = *(const f16x8*)&Bh[(wc * 64 + lq) * 72 + ko];
      f16x8 bh1 = *(const f16x8*)&Bh[(wc * 64 + 16 + lq) * 72 + ko];
      f16x8 bh2 = *(const f16x8*)&Bh[(wc * 64 + 32 + lq) * 72 + ko];
      f16x8 bh3 = *(const f16x8*)&Bh[(wc * 64 + 48 + lq) * 72 + ko];
#pragma unroll
      for (int i = 0; i < 2; i++) {
        f16x8 ahv = *(const f16x8*)&Ah[(wr * 32 + i * 16 + lq) * 72 + ko];
        acc[i][0] = MFMAH16(ahv, bh0, acc[i][0]);
        acc[i][1] = MFMAH16(ahv, bh1, acc[i][1]);
        acc[i][2] = MFMAH16(ahv, bh2, acc[i][2]);
        acc[i][3] = MFMAH16(ahv, bh3, acc[i][3]);
      }
    }
  }

  ushort_t* dqk = (z == 0) ? Qf : Kf;
#pragma unroll
  for (int i = 0; i < 2; i++)
#pragma unroll
    for (int j = 0; j < 4; j++)
#pragma unroll
      for (int ri = 0; ri < 4; ri++) {
        int m = m0 + wr * 32 + i * 16 + 4 * lg + ri;
        int e = n0 + wc * 64 + j * 16 + lq;
        float v = acc[i][j][ri] + bias[e];
        int l = m >> 1, n = m & 1, hh = e >> 6, d = e & 63;
        if (z == 2) {
          Vt[((size_t)(n * 16 + hh) * 64 + d) * 2048 + l] = f2h(v);
        } else {
          // Q scale = 1/sqrt(64) * log2(e): scores land in exp2 domain
          float x = (z == 0) ? v * (0.125f * 1.4426950408889634f) : v;
          dqk[((size_t)(n * 16 + hh) * 2048 + l) * 64 + d] = f2h(x);
        }
      }
}

// ------ output projection: A-side = AO2[h][m][d] (h-major), B = WoP ------
__global__ __launch_bounds__(256, 4) void proj_out(
    const ushort_t* __restrict__ AOhi, const ushort_t* __restrict__ AOlo,
    const ushort_t* __restrict__ Whi3, const ushort_t* __restrict__ Wlo3,
    const float* __restrict__ bias, float* __restrict__ out) {
  __shared__ ushort_t Ah[64 * 72], Al[64 * 72], Bh[64 * 72], Bl[64 * 72];
  const int tid = threadIdx.x;
  const int n0 = blockIdx.x * 64, m0 = blockIdx.y * 64;
  const int lane = tid & 63, wv = tid >> 6;
  const int lg = lane >> 4, lq = lane & 15;
  const int wr = wv >> 1, wc = wv & 1;
  const int sr = tid >> 2, c8 = (tid & 3) * 8;

  f32x4 acc[2][2] = {};

  const size_t abase = (size_t)(m0 + sr) * 64 + c8;
  const ushort_t* Bhg = Whi3 + (size_t)(n0 + sr) * 1024 + c8;
  const ushort_t* Blg = Wlo3 + (size_t)(n0 + sr) * 1024 + c8;

  bf16x8 pa0 = *(const bf16x8*)&AOhi[abase], pa1 = *(const bf16x8*)&AOhi[abase + 32];
  bf16x8 pc0 = *(const bf16x8*)&AOlo[abase], pc1 = *(const bf16x8*)&AOlo[abase + 32];
  bf16x8 pb0 = *(const bf16x8*)&Bhg[0], pb1 = *(const bf16x8*)&Bhg[32];
  bf16x8 pl0 = *(const bf16x8*)&Blg[0], pl1 = *(const bf16x8*)&Blg[32];

  for (int k0 = 0; k0 < 1024; k0 += 64) {
    __syncthreads();
    *(bf16x8*)&Ah[sr * 72 + c8] = pa0;  *(bf16x8*)&Ah[sr * 72 + c8 + 32] = pa1;
    *(bf16x8*)&Al[sr * 72 + c8] = pc0;  *(bf16x8*)&Al[sr * 72 + c8 + 32] = pc1;
    *(bf16x8*)&Bh[sr * 72 + c8] = pb0;  *(bf16x8*)&Bh[sr * 72 + c8 + 32] = pb1;
    *(bf16x8*)&Bl[sr * 72 + c8] = pl0;  *(bf16x8*)&Bl[sr * 72 + c8 + 32] = pl1;
    if (k0 + 64 < 1024) {
      const size_t an = abase + (size_t)((k0 >> 6) + 1) * 262144;
      pa0 = *(const bf16x8*)&AOhi[an]; pa1 = *(const bf16x8*)&AOhi[an + 32];
      pc0 = *(const bf16x8*)&AOlo[an]; pc1 = *(const bf16x8*)&AOlo[an + 32];
      pb0 = *(const bf16x8*)&Bhg[k0 + 64]; pb1 = *(const bf16x8*)&Bhg[k0 + 96];
      pl0 = *(const bf16x8*)&Blg[k0 + 64]; pl1 = *(const bf16x8*)&Blg[k0 + 96];
    }
    __syncthreads();
#pragma unroll
    for (int kh = 0; kh < 2; kh++) {
      const int ko = kh * 32 + lg * 8;
      bf16x8 bh0 = *(const bf16x8*)&Bh[(wc * 32 + lq) * 72 + ko];
      bf16x8 bh1 = *(const bf16x8*)&Bh[(wc * 32 + 16 + lq) * 72 + ko];
      bf16x8 bl0 = *(const bf16x8*)&Bl[(wc * 32 + lq) * 72 + ko];
      bf16x8 bl1 = *(const bf16x8*)&Bl[(wc * 32 + 16 + lq) * 72 + ko];
#pragma unroll
      for (int i = 0; i < 2; i++) {
        bf16x8 ahv = *(const bf16x8*)&Ah[(wr * 32 + i * 16 + lq) * 72 + ko];
        bf16x8 alv = *(const bf16x8*)&Al[(wr * 32 + i * 16 + lq) * 72 + ko];
        acc[i][0] = MFMA16(ahv, bh0, acc[i][0]);
        acc[i][0] = MFMA16(alv, bh0, acc[i][0]);
        acc[i][0] = MFMA16(ahv, bl0, acc[i][0]);
        acc[i][1] = MFMA16(ahv, bh1, acc[i][1]);
        acc[i][1] = MFMA16(alv, bh1, acc[i][1]);
        acc[i][1] = MFMA16(ahv, bl1, acc[i][1]);
      }
    }
  }

#pragma unroll
  for (int i = 0; i < 2; i++)
#pragma unroll
    for (int j = 0; j < 2; j++)
#pragma unroll
      for (int ri = 0; ri < 4; ri++) {
        int m = m0 + wr * 32 + i * 16 + 4 * lg + ri;
        int e = n0 + wc * 32 + j * 16 + lq;
        out[(size_t)m * 1024 + e] = acc[i][j][ri] + bias[e];
      }
}

// scan a packed-u16 256-bin hist row for the bin containing rank `target`.
// RANKMAP=true: hist is indexed by RAW fp16 top-8 bits; traverse in
// decreasing-VALUE order (raw 0x7F..0x00 then 0x80..0xFF). Output bin is a
// RANK in 0..255. RANKMAP=false: hist already rank-ordered.
template <bool RANKMAP>
__device__ __forceinline__ void scan_row(const unsigned* hrow, unsigned target,
                                         int lane, int* binOut, unsigned* remOut) {
  unsigned c0, c1, c2, c3;
  if (RANKMAP) {
    const bool neg = lane >= 32;
    const int ho = neg ? (lane << 1) : (62 - (lane << 1));
    uint2 hw = *(const uint2*)&hrow[ho];
    unsigned a0 = hw.x & 0xffffu, a1 = hw.x >> 16;
    unsigned a2 = hw.y & 0xffffu, a3 = hw.y >> 16;
    c0 = neg ? a0 : a3; c1 = neg ? a1 : a2;
    c2 = neg ? a2 : a1; c3 = neg ? a3 : a0;
  } else {
    uint2 hw = *(const uint2*)&hrow[lane << 1];
    c0 = hw.x & 0xffffu; c1 = hw.x >> 16;
    c2 = hw.y & 0xffffu; c3 = hw.y >> 16;
  }
  unsigned s4 = c0 + c1 + c2 + c3, incl = s4;
#pragma unroll
  for (int off = 1; off < 64; off <<= 1) {
    unsigned t = __shfl_up(incl, off);
    if (lane >= off) incl += t;
  }
  unsigned excl = incl - s4;
  bool found = (excl < target) && (target <= incl);
  int b = 0; unsigned rm = 1;
  if (found) {
    unsigned cum = excl;
    if (cum + c0 >= target) { b = (lane << 2); rm = target - cum; }
    else { cum += c0;
      if (cum + c1 >= target) { b = (lane << 2) + 1; rm = target - cum; }
      else { cum += c1;
        if (cum + c2 >= target) { b = (lane << 2) + 2; rm = target - cum; }
        else { cum += c2; b = (lane << 2) + 3; rm = target - cum; } } }
  }
  unsigned long long bal = __ballot(found);
  int src = (int)__builtin_ctzll(bal);
  *binOut = __shfl(b, src);
  *remOut = (unsigned)__shfl((int)rm, src);
}

// ---- P1 macros: fp16 K frag loads (per-lane base + const offsets) ----
#define KLOAD(F, gg)                                                   \
  do {                                                                 \
    _Pragma("unroll") for (int tt = 0; tt < 4; tt++) {                 \
      const int koff = ((gg) * 4 + tt) * 1024;                         \
      F[tt * 2 + 0] = *(const f16x8*)&kbase[koff];                     \
      F[tt * 2 + 1] = *(const f16x8*)&kbase[koff + 32];                \
    }                                                                  \
  } while (0)

// C = K·Q^T -> C[row=s_loc=4lg+ri][col=q=lq]; fp16 score + RAW top-8 hist
// (rank mapping deferred to P2's scan — no key math per score)
#define KCOMP(F, gg)                                                          \
  do {                                                                        \
    _Pragma("unroll") for (int tt = 0; tt < 4; tt++) {                        \
      f32x4 acc_ = {0.f, 0.f, 0.f, 0.f};                                      \
      acc_ = MFMAH16(F[tt * 2 + 0], qf0, acc_);                               \
      acc_ = MFMAH16(F[tt * 2 + 1], qf1, acc_);                               \
      uint2 pw_;                                                              \
      pw_.x = (unsigned)f2h(acc_[0]) | ((unsigned)f2h(acc_[1]) << 16);        \
      pw_.y = (unsigned)f2h(acc_[2]) | ((unsigned)f2h(acc_[3]) << 16);        \
      atomicAdd(&histP[lq * HSTR + ((pw_.x >> 9) & 0x7Fu)],                   \
                1u << (((pw_.x >> 8) & 1u) << 4));                            \
      atomicAdd(&histP[lq * HSTR + (pw_.x >> 25)],                            \
                1u << (((pw_.x >> 24) & 1u) << 4));                           \
      atomicAdd(&histP[lq * HSTR + ((pw_.y >> 9) & 0x7Fu)],                   \
                1u << (((pw_.y >> 8) & 1u) << 4));                            \
      atomicAdd(&histP[lq * HSTR + (pw_.y >> 25)],                            \
                1u << (((pw_.y >> 24) & 1u) << 4));                           \
      const int st_ = (w * 16 + (gg) * 4 + tt) * 16;                          \
      *(uint2*)&scH[lq * SROW + ((st_ + 4 * lg) ^ xr8q)] = pw_;               \
    }                                                                         \
  } while (0)

// One WG = 512 thr (8 waves) per (n, h, 16 q-rows). 76.6 KB LDS => 2 WG/CU,
// 16 waves/CU (4/SIMD). Two independent WGs interleave across barriers.
__global__ __launch_bounds__(512, 4) void sparse_attn(
    const ushort_t* __restrict__ Qf, const ushort_t* __restrict__ Kfp,
    const ushort_t* __restrict__ Vt, ushort_t* __restrict__ AOhi,
    ushort_t* __restrict__ AOlo) {
  __shared__ ushort_t scH[16 * SROW];   // 65536 B fp16 scores, then fp16 P
  __shared__ unsigned histP[16 * HSTR]; // 8448 B packed u16x2 counts (RAW bins)
  __shared__ float Obuf[16 * 68];       // 4352 B partial O [q][d]
  __shared__ float dinvS[16];

  // bijective XCD swizzle: each XCD owns a contiguous 512-block range
  const int flat = blockIdx.x + 128 * (blockIdx.y + 16 * blockIdx.z);
  const int idx = (flat & 7) * 512 + (flat >> 3);
  const int lb = idx & 127, h = (idx >> 7) & 15, n = idx >> 11;

  const int tid = threadIdx.x;
  const int lane = tid & 63, w = tid >> 6;  // w 0..7
  const int lg = lane >> 4, lq = lane & 15;
  const int xr8q = (lq & 7) << 3;
  const size_t nh = (size_t)(n * 16 + h);

  for (int i = tid; i < 16 * HSTR; i += 512) histP[i] = 0u;
  for (int i = tid; i < 16 * 68; i += 512) Obuf[i] = 0.f;

  // Q frags (fp16, pre-scaled incl. log2e): B-operand B[k=d][c=q=lq]
  const size_t qo = (nh * 2048 + (size_t)lb * 16 + lq) * 64 + lg * 8;
  const f16x8 qf0 = *(const f16x8*)&Qf[qo];
  const f16x8 qf1 = *(const f16x8*)&Qf[qo + 32];

  const ushort_t* Kf = Kfp + nh * 2048 * 64;
  const ushort_t* kbase = Kf + (size_t)(w * 256 + lq) * 64 + lg * 8;

  // first K-group issued BEFORE the zero-barrier (overlaps LDS zeroing)
  f16x8 fa[8], fb[8];
  KLOAD(fa, 0);

  __syncthreads();  // hist + Obuf zeroed

  // ---------------- Phase 1: 16 s-tiles per wave ----------------
  {
    for (int g = 0; g < 4; g += 2) {
      KLOAD(fb, g + 1);
      KCOMP(fa, g);
      if (g + 2 < 4) KLOAD(fa, g + 2);
      KCOMP(fb, g + 1);
    }
  }
  __syncthreads();  // scores + hist complete

  // ---- P3 V-quad prefetch (global, independent of P2) ----
  const int db3 = w & 3, sh3 = w >> 2;
  const int sOff3 = sh3 * 1024;
  const ushort_t* Vb = Vt + (nh * 64 + (size_t)(db3 * 16 + lq)) * 2048 + sOff3;
  f16x8 pv0 = *(const f16x8*)&Vb[lg * 8];
  f16x8 pv1 = *(const f16x8*)&Vb[32 + lg * 8];
  f16x8 pv2 = *(const f16x8*)&Vb[64 + lg * 8];
  f16x8 pv3 = *(const f16x8*)&Vb[96 + lg * 8];

  // -------- Phase 2: rows r0=2w, r1=2w+1, fully interleaved --------
  {
    const int r0 = w * 2, r1 = r0 + 1;
    const int ba = r0 * SROW, bb = r1 * SROW;
    const int xa = (r0 & 7) << 3, xb = (r1 & 7) << 3;
    unsigned* hrow0 = &histP[r0 * HSTR];
    unsigned* hrow1 = &histP[r1 * HSTR];

    // issue all score reads (4 uint4 per row)
    uint4 rA0 = *(const uint4*)&scH[ba + ((0 * 512 + lane * 8) ^ xa)];
    uint4 rA1 = *(const uint4*)&scH[ba + ((1 * 512 + lane * 8) ^ xa)];
    uint4 rA2 = *(const uint4*)&scH[ba + ((2 * 512 + lane * 8) ^ xa)];
    uint4 rA3 = *(const uint4*)&scH[ba + ((3 * 512 + lane * 8) ^ xa)];
    uint4 rB0 = *(const uint4*)&scH[bb + ((0 * 512 + lane * 8) ^ xb)];
    uint4 rB1 = *(const uint4*)&scH[bb + ((1 * 512 + lane * 8) ^ xb)];
    uint4 rB2 = *(const uint4*)&scH[bb + ((2 * 512 + lane * 8) ^ xb)];
    uint4 rB3 = *(const uint4*)&scH[bb + ((3 * 512 + lane * 8) ^ xb)];

    // coarse scans, both rows (independent chains)
    int b1a, b1b; unsigned rema, remb;
    scan_row<true>(hrow0, KSEL, lane, &b1a, &rema);
    scan_row<true>(hrow1, KSEL, lane, &b1b, &remb);
    const unsigned rba = (b1a < 128) ? (unsigned)(b1a ^ 0x7F) : (unsigned)b1a;
    const unsigned sxa = (rba & 0x80u) ? 0u : 0xFFu;
    const unsigned rbb = (b1b < 128) ? (unsigned)(b1b ^ 0x7F) : (unsigned)b1b;
    const unsigned sxb = (rbb & 0x80u) ? 0u : 0xFFu;

    // zero both refine windows, ONE fence
    *(uint2*)&hrow0[lane << 1] = make_uint2(0u, 0u);
    *(uint2*)&hrow1[lane << 1] = make_uint2(0u, 0u);
    __threadfence_block();

    auto refine = [&](unsigned wd, unsigned rbx, unsigned sxx, unsigned* hr) {
      if (((wd >> 8) & 0xFFu) == rbx) {
        unsigned s_ = (wd & 0xFFu) ^ sxx;
        atomicAdd(&hr[s_ >> 1], 1u << ((s_ & 1u) << 4));
      }
      if ((wd >> 24) == rbx) {
        unsigned s_ = ((wd >> 16) & 0xFFu) ^ sxx;
        atomicAdd(&hr[s_ >> 1], 1u << ((s_ & 1u) << 4));
      }
    };
    refine(rA0.x, rba, sxa, hrow0); refine(rB0.x, rbb, sxb, hrow1);
    refine(rA0.y, rba, sxa, hrow0); refine(rB0.y, rbb, sxb, hrow1);
    refine(rA0.z, rba, sxa, hrow0); refine(rB0.z, rbb, sxb, hrow1);
    refine(rA0.w, rba, sxa, hrow0); refine(rB0.w, rbb, sxb, hrow1);
    refine(rA1.x, rba, sxa, hrow0); refine(rB1.x, rbb, sxb, hrow1);
    refine(rA1.y, rba, sxa, hrow0); refine(rB1.y, rbb, sxb, hrow1);
    refine(rA1.z, rba, sxa, hrow0); refine(rB1.z, rbb, sxb, hrow1);
    refine(rA1.w, rba, sxa, hrow0); refine(rB1.w, rbb, sxb, hrow1);
    refine(rA2.x, rba, sxa, hrow0); refine(rB2.x, rbb, sxb, hrow1);
    refine(rA2.y, rba, sxa, hrow0); refine(rB2.y, rbb, sxb, hrow1);
    refine(rA2.z, rba, sxa, hrow0); refine(rB2.z, rbb, sxb, hrow1);
    refine(rA2.w, rba, sxa, hrow0); refine(rB2.w, rbb, sxb, hrow1);
    refine(rA3.x, rba, sxa, hrow0); refine(rB3.x, rbb, sxb, hrow1);
    refine(rA3.y, rba, sxa, hrow0); refine(rB3.y, rbb, sxb, hrow1);
    refine(rA3.z, rba, sxa, hrow0); refine(rB3.z, rbb, sxb, hrow1);
    refine(rA3.w, rba, sxa, hrow0); refine(rB3.w, rbb, sxb, hrow1);
    __threadfence_block();

    // fine scans, both rows
    int b2a, b2b; unsigned dum;
    scan_row<false>(hrow0, rema, lane, &b2a, &dum);
    scan_row<false>(hrow1, remb, lane, &b2b, &dum);
    const float fVa = h2f((ushort_t)((rba << 8) | (((unsigned)b2a) ^ sxa)));
    const float fVb = h2f((ushort_t)((rbb << 8) | (((unsigned)b2b) ^ sxb)));

    // exp2 passes, both rows (scores pre-scaled by log2e)
    float dena = 0.f, denb = 0.f;
    auto expw = [&](unsigned wd, float fVx, float& dn) -> unsigned {
      float f0 = h2f((ushort_t)(wd & 0xffffu));
      float f1 = h2f((ushort_t)(wd >> 16));
      float e0 = (f0 >= fVx) ? __builtin_amdgcn_exp2f(f0) : 0.f;
      float e1 = (f1 >= fVx) ? __builtin_amdgcn_exp2f(f1) : 0.f;
      dn += e0 + e1;
      return (unsigned)f2h(e0) | ((unsigned)f2h(e1) << 16);
    };
    uint4 oa, ob;
    oa.x = expw(rA0.x, fVa, dena); ob.x = expw(rB0.x, fVb, denb);
    oa.y = expw(rA0.y, fVa, dena); ob.y = expw(rB0.y, fVb, denb);
    oa.z = expw(rA0.z, fVa, dena); ob.z = expw(rB0.z, fVb, denb);
    oa.w = expw(rA0.w, fVa, dena); ob.w = expw(rB0.w, fVb, denb);
    *(uint4*)&scH[ba + ((0 * 512 + lane * 8) ^ xa)] = oa;
    *(uint4*)&scH[bb + ((0 * 512 + lane * 8) ^ xb)] = ob;
    oa.x = expw(rA1.x, fVa, dena); ob.x = expw(rB1.x, fVb, denb);
    oa.y = expw(rA1.y, fVa, dena); ob.y = expw(rB1.y, fVb, denb);
    oa.z = expw(rA1.z, fVa, dena); ob.z = expw(rB1.z, fVb, denb);
    oa.w = expw(rA1.w, fVa, dena); ob.w = expw(rB1.w, fVb, denb);
    *(uint4*)&scH[ba + ((1 * 512 + lane * 8) ^ xa)] = oa;
    *(uint4*)&scH[bb + ((1 * 512 + lane * 8) ^ xb)] = ob;
    oa.x = expw(rA2.x, fVa, dena); ob.x = expw(rB2.x, fVb, denb);
    oa.y = expw(rA2.y, fVa, dena); ob.y = expw(rB2.y, fVb, denb);
    oa.z = expw(rA2.z, fVa, dena); ob.z = expw(rB2.z, fVb, denb);
    oa.w = expw(rA2.w, fVa, dena); ob.w = expw(rB2.w, fVb, denb);
    *(uint4*)&scH[ba + ((2 * 512 + lane * 8) ^ xa)] = oa;
    *(uint4*)&scH[bb + ((2 * 512 + lane * 8) ^ xb)] = ob;
    oa.x = expw(rA3.x, fVa, dena); ob.x = expw(rB3.x, fVb, denb);
    oa.y = expw(rA3.y, fVa, dena); ob.y = expw(rB3.y, fVb, denb);
    oa.z = expw(rA3.z, fVa, dena); ob.z = expw(rB3.z, fVb, denb);
    oa.w = expw(rA3.w, fVa, dena); ob.w = expw(rB3.w, fVb, denb);
    *(uint4*)&scH[ba + ((3 * 512 + lane * 8) ^ xa)] = oa;
    *(uint4*)&scH[bb + ((3 * 512 + lane * 8) ^ xb)] = ob;

#pragma unroll
    for (int off = 32; off > 0; off >>= 1) {
      dena += __shfl_xor(dena, off);
      denb += __shfl_xor(denb, off);
    }
    if (lane == 0) {
      dinvS[r0] = 1.0f / dena;
      dinvS[r1] = 1.0f / denb;
    }
  }
  __syncthreads();  // P + dinvS ready

  // ---- Phase 3: PV quadrant (d-block w&3, s-half w>>2), 3-deep prefetch ----
  {
    const int xw = (lq & 7) << 3;
    const int arow = lq * SROW;
    f32x4 o0 = {0.f, 0.f, 0.f, 0.f}, o1 = o0, o2 = o0, o3 = o0;
    f16x8 va0 = pv0, va1 = pv1, vb0 = pv2, vb1 = pv3;
#pragma unroll 2
    for (int c = 0; c < 16; c += 2) {
      f16x8 na0, na1, nb0, nb1;
      if (c + 2 < 16) {
        na0 = *(const f16x8*)&Vb[(c + 2) * 64 + lg * 8];
        na1 = *(const f16x8*)&Vb[(c + 2) * 64 + 32 + lg * 8];
        nb0 = *(const f16x8*)&Vb[(c + 3) * 64 + lg * 8];
        nb1 = *(const f16x8*)&Vb[(c + 3) * 64 + 32 + lg * 8];
      }
      f16x8 pa0 = *(const f16x8*)&scH[arow + ((sOff3 + c * 64 + lg * 8) ^ xw)];
      f16x8 pa1 = *(const f16x8*)&scH[arow + ((sOff3 + c * 64 + 32 + lg * 8) ^ xw)];
      o0 = MFMAH16(pa0, va0, o0);
      o1 = MFMAH16(pa1, va1, o1);
      f16x8 pb0_ = *(const f16x8*)&scH[arow + ((sOff3 + (c + 1) * 64 + lg * 8) ^ xw)];
      f16x8 pb1_ = *(const f16x8*)&scH[arow + ((sOff3 + (c + 1) * 64 + 32 + lg * 8) ^ xw)];
      o2 = MFMAH16(pb0_, vb0, o2);
      o3 = MFMAH16(pb1_, vb1, o3);
      va0 = na0; va1 = na1; vb0 = nb0; vb1 = nb1;
    }
    f32x4 oa = (o0 + o1) + (o2 + o3);
#pragma unroll
    for (int ri = 0; ri < 4; ri++) {
      int q = lg * 4 + ri;
      atomicAdd(&Obuf[q * 68 + db3 * 16 + lq], oa[ri]);
    }
  }
  __syncthreads();  // partial O combined

  // ---- epilogue: scale by 1/den, write AO2[h][m][d] (line-dense) ----
  {
#pragma unroll
    for (int rep = 0; rep < 2; rep++) {
      int idx2 = tid + rep * 512;
      int q = idx2 >> 6, d = idx2 & 63;
      float val = Obuf[q * 68 + d] * dinvS[q];
      size_t ai = ((size_t)h * 4096 + (size_t)(lb * 16 + q) * 2 + n) * 64 +
                  (size_t)d;
      ushort_t hb = f2bf(val);
      AOhi[ai] = hb;
      AOlo[ai] = f2bf(val - bf2f(hb));
    }
  }
}

extern "C" void kernel_launch(void* const* d_in, const int* in_sizes, int n_in,
                              void* d_out, int out_size, void* d_ws, size_t ws_size,
                              hipStream_t stream) {
  const float* query = (const float*)d_in[0];
  const float* key   = (const float*)d_in[1];
  const float* value = (const float*)d_in[2];
  const float* Wq    = (const float*)d_in[3];
  const float* bq    = (const float*)d_in[4];
  const float* Wk    = (const float*)d_in[5];
  const float* bk    = (const float*)d_in[6];
  const float* Wv    = (const float*)d_in[7];
  const float* bv    = (const float*)d_in[8];
  const float* Wo    = (const float*)d_in[9];
  const float* bo    = (const float*)d_in[10];

  ushort_t* Qf   = (ushort_t*)d_ws;
  ushort_t* Kf   = Qf + 4194304;
  ushort_t* Vt   = Kf + 4194304;
  ushort_t* AOhi = Vt + 4194304;
  ushort_t* AOlo = AOhi + 4194304;
  ushort_t* Whi  = AOlo + 4194304;
  ushort_t* Wlo  = Whi + 4194304;

  dim3 block(256);
  presplit_w<<<dim3(512, 4), block, 0, stream>>>(Wq, Wk, Wv, Wo, Whi, Wlo);

  proj_qkv<<<dim3(8, 64, 3), block, 0, stream>>>(query, key, value, bq, bk, bv,
                                                 Whi, Qf, Kf, Vt);

  sparse_attn<<<dim3(128, 16, 2), dim3(512), 0, stream>>>(Qf, Kf, Vt, AOhi, AOlo);

  proj_out<<<dim3(16, 64), block, 0, stream>>>(AOhi, AOlo, Whi + 3 * 1048576,
                                               Wlo + 3 * 1048576, bo,
                                               (float*)d_out);
}

// Round 5
// 381.046 us; speedup vs baseline: 1.0044x; 1.0044x over previous
//
#include <hip/hip_runtime.h>
#include <hip/hip_bf16.h>
#include <hip/hip_fp16.h>

// MultiHeadSparseAttention. R22 = R20 exact (best measured: 268us attn)
// + ONLY the two safe latency hoists from R21, with launch_bounds(512,2)
// kept so the register budget (256) never forces re-scheduling:
//   - first KLOAD issued before the zero-fill barrier (K latency hides
//     under hist/Obuf zeroing)
//   - P3's first V-quad issued before P2 (V latency hides under P2's
//     ~2us VALU/DS phase; +16 VGPR held, still ~70 total)
// R21's P2 dual-row interleave + (512,4) cap is REVERTED (cost 26us:
// compiler undid the interleave under register pressure).
//   P1: wave w -> 16 s-tiles (s in [w*256, w*256+256))
//   P2: wave w -> rows 2w, 2w+1 (scan + refine + exp pass, per-row)
//   P3: wave w -> (d-block w&3, s-half w>>2); f32-atomic combine in Obuf
// L=S=2048, N=2, E=1024, H=16, D=64, k_sel = int(2048*sigmoid(0.3)) = 1176.
//
// ws (halfwords): Qf 4M | Kf 4M | Vt 4M | AOhi 4M | AOlo 4M | Whi 4M | Wlo 4M

#define KSEL 1176u
#define SROW 2048  // fp16 score row stride (elements) — bank-aligned rows
#define HSTR 132   // hist row stride in u32

typedef __attribute__((ext_vector_type(8))) short bf16x8;
typedef __attribute__((ext_vector_type(8))) _Float16 f16x8;
typedef __attribute__((ext_vector_type(4))) float f32x4;
typedef unsigned short ushort_t;

union S8 { bf16x8 v; ushort_t u[8]; };
union H8 { f16x8 v; ushort_t u[8]; };

#define MFMA16(A, B, C)  __builtin_amdgcn_mfma_f32_16x16x32_bf16(A, B, C, 0, 0, 0)
#define MFMAH16(A, B, C) __builtin_amdgcn_mfma_f32_16x16x32_f16(A, B, C, 0, 0, 0)

__device__ __forceinline__ ushort_t f2bf(float x) {  // RNE f32->bf16
  unsigned u = __float_as_uint(x);
  return (ushort_t)((u + 0x7FFFu + ((u >> 16) & 1u)) >> 16);
}
__device__ __forceinline__ float bf2f(ushort_t b) {
  return __uint_as_float(((unsigned)b) << 16);
}
__device__ __forceinline__ ushort_t f2h(float x) {
  return __half_as_ushort(__float2half(x));
}
__device__ __forceinline__ float h2f(ushort_t b) {
  return __half2float(__ushort_as_half(b));
}

// convert 8 fp32 (two float4) to fp16, store as f16x8
__device__ __forceinline__ void cvt8(ushort_t* dst, float4 p, float4 q) {
  H8 t;
  t.u[0] = f2h(p.x); t.u[1] = f2h(p.y); t.u[2] = f2h(p.z); t.u[3] = f2h(p.w);
  t.u[4] = f2h(q.x); t.u[5] = f2h(q.y); t.u[6] = f2h(q.z); t.u[7] = f2h(q.w);
  *(f16x8*)dst = t.v;
}

// ---- W prep: Wq/Wk/Wv -> fp16 (Whi only); Wo -> bf16 hi/lo PERMUTED ----
__global__ __launch_bounds__(256) void presplit_w(
    const float* __restrict__ W0, const float* __restrict__ W1,
    const float* __restrict__ W2, const float* __restrict__ W3,
    ushort_t* __restrict__ Whi, ushort_t* __restrict__ Wlo) {
  const int m = blockIdx.y;
  const float* W = (m == 0) ? W0 : (m == 1) ? W1 : (m == 2) ? W2 : W3;
  const size_t off = ((size_t)blockIdx.x * 256 + threadIdx.x) * 8;
  const size_t base = (size_t)m * 1048576 + off;
  if (m == 3) {
    const int f = (int)(off >> 10);
    const int r = (int)(off & 1023);
    const int hcol = r >> 6, d0 = r & 63;
    S8 hi_, lo_;
#pragma unroll
    for (int j = 0; j < 8; j++) {
      float x = W[(size_t)f * 1024 + (size_t)(d0 + j) * 16 + hcol];
      ushort_t hb = f2bf(x);
      hi_.u[j] = hb;
      lo_.u[j] = f2bf(x - bf2f(hb));
    }
    *(bf16x8*)&Whi[base] = hi_.v;
    *(bf16x8*)&Wlo[base] = lo_.v;
  } else {
    float4 p = *(const float4*)&W[off];
    float4 q = *(const float4*)&W[off + 4];
    cvt8(&Whi[base], p, q);
  }
}

// -------- fused Q/K/V projection: 64x128 tile, plain fp16, 1 MFMA --------
__global__ __launch_bounds__(256, 4) void proj_qkv(
    const float* __restrict__ Xq, const float* __restrict__ Xk,
    const float* __restrict__ Xv, const float* __restrict__ bq,
    const float* __restrict__ bk, const float* __restrict__ bv,
    const ushort_t* __restrict__ Whi, ushort_t* __restrict__ Qf,
    ushort_t* __restrict__ Kf, ushort_t* __restrict__ Vt) {
  __shared__ ushort_t Ah[64 * 72], Bh[128 * 72];
  const int z = blockIdx.z;
  const float* X = (z == 0) ? Xq : (z == 1) ? Xk : Xv;
  const float* bias = (z == 0) ? bq : (z == 1) ? bk : bv;
  const size_t zoff = (size_t)z * 1048576;

  const int tid = threadIdx.x;
  const int n0 = blockIdx.x * 128, m0 = blockIdx.y * 64;
  const int lane = tid & 63, wv = tid >> 6;
  const int lg = lane >> 4, lq = lane & 15;
  const int wr = wv >> 1, wc = wv & 1;
  const int sr = tid >> 2, c8 = (tid & 3) * 8;

  f32x4 acc[2][4] = {};

  const float* Xr = &X[(size_t)(m0 + sr) * 1024 + c8];
  const ushort_t* Bg0 = Whi + zoff + (size_t)(n0 + sr) * 1024 + c8;
  const ushort_t* Bg1 = Bg0 + 64 * 1024;

  float4 a0 = *(const float4*)&Xr[0],  a1 = *(const float4*)&Xr[4];
  float4 a2 = *(const float4*)&Xr[32], a3 = *(const float4*)&Xr[36];
  f16x8 pb0 = *(const f16x8*)&Bg0[0], pb1 = *(const f16x8*)&Bg0[32];
  f16x8 pb2 = *(const f16x8*)&Bg1[0], pb3 = *(const f16x8*)&Bg1[32];

  for (int k0 = 0; k0 < 1024; k0 += 64) {
    __syncthreads();
    cvt8(&Ah[sr * 72 + c8], a0, a1);
    cvt8(&Ah[sr * 72 + c8 + 32], a2, a3);
    *(f16x8*)&Bh[sr * 72 + c8] = pb0;
    *(f16x8*)&Bh[sr * 72 + c8 + 32] = pb1;
    *(f16x8*)&Bh[(64 + sr) * 72 + c8] = pb2;
    *(f16x8*)&Bh[(64 + sr) * 72 + c8 + 32] = pb3;
    if (k0 + 64 < 1024) {
      const float* Xn = Xr + k0 + 64;
      a0 = *(const float4*)&Xn[0];  a1 = *(const float4*)&Xn[4];
      a2 = *(const float4*)&Xn[32]; a3 = *(const float4*)&Xn[36];
      pb0 = *(const f16x8*)&Bg0[k0 + 64];
      pb1 = *(const f16x8*)&Bg0[k0 + 96];
      pb2 = *(const f16x8*)&Bg1[k0 + 64];
      pb3 = *(const f16x8*)&Bg1[k0 + 96];
    }
    __syncthreads();
#pragma unroll
    for (int kh = 0; kh < 2; kh++) {
      const int ko = kh * 32 + lg * 8;
      f16x8 bh0 = *(const f16x8*)&Bh[(wc * 64 + lq) * 72 + ko];
      f16x8 bh1 = *(const f16x8*)&Bh[(wc * 64 + 16 + lq) * 72 + ko];
      f16x8 bh2 = *(const f16x8*)&Bh[(wc * 64 + 32 + lq) * 72 + ko];
      f16x8 bh3 = *(const f16x8*)&Bh[(wc * 64 + 48 + lq) * 72 + ko];
#pragma unroll
      for (int i = 0; i < 2; i++) {
        f16x8 ahv = *(const f16x8*)&Ah[(wr * 32 + i * 16 + lq) * 72 + ko];
        acc[i][0] = MFMAH16(ahv, bh0, acc[i][0]);
        acc[i][1] = MFMAH16(ahv, bh1, acc[i][1]);
        acc[i][2] = MFMAH16(ahv, bh2, acc[i][2]);
        acc[i][3] = MFMAH16(ahv, bh3, acc[i][3]);
      }
    }
  }

  ushort_t* dqk = (z == 0) ? Qf : Kf;
#pragma unroll
  for (int i = 0; i < 2; i++)
#pragma unroll
    for (int j = 0; j < 4; j++)
#pragma unroll
      for (int ri = 0; ri < 4; ri++) {
        int m = m0 + wr * 32 + i * 16 + 4 * lg + ri;
        int e = n0 + wc * 64 + j * 16 + lq;
        float v = acc[i][j][ri] + bias[e];
        int l = m >> 1, n = m & 1, hh = e >> 6, d = e & 63;
        if (z == 2) {
          Vt[((size_t)(n * 16 + hh) * 64 + d) * 2048 + l] = f2h(v);
        } else {
          // Q scale = 1/sqrt(64) * log2(e): scores land in exp2 domain
          float x = (z == 0) ? v * (0.125f * 1.4426950408889634f) : v;
          dqk[((size_t)(n * 16 + hh) * 2048 + l) * 64 + d] = f2h(x);
        }
      }
}

// ------ output projection: A-side = AO2[h][m][d] (h-major), B = WoP ------
__global__ __launch_bounds__(256, 4) void proj_out(
    const ushort_t* __restrict__ AOhi, const ushort_t* __restrict__ AOlo,
    const ushort_t* __restrict__ Whi3, const ushort_t* __restrict__ Wlo3,
    const float* __restrict__ bias, float* __restrict__ out) {
  __shared__ ushort_t Ah[64 * 72], Al[64 * 72], Bh[64 * 72], Bl[64 * 72];
  const int tid = threadIdx.x;
  const int n0 = blockIdx.x * 64, m0 = blockIdx.y * 64;
  const int lane = tid & 63, wv = tid >> 6;
  const int lg = lane >> 4, lq = lane & 15;
  const int wr = wv >> 1, wc = wv & 1;
  const int sr = tid >> 2, c8 = (tid & 3) * 8;

  f32x4 acc[2][2] = {};

  const size_t abase = (size_t)(m0 + sr) * 64 + c8;
  const ushort_t* Bhg = Whi3 + (size_t)(n0 + sr) * 1024 + c8;
  const ushort_t* Blg = Wlo3 + (size_t)(n0 + sr) * 1024 + c8;

  bf16x8 pa0 = *(const bf16x8*)&AOhi[abase], pa1 = *(const bf16x8*)&AOhi[abase + 32];
  bf16x8 pc0 = *(const bf16x8*)&AOlo[abase], pc1 = *(const bf16x8*)&AOlo[abase + 32];
  bf16x8 pb0 = *(const bf16x8*)&Bhg[0], pb1 = *(const bf16x8*)&Bhg[32];
  bf16x8 pl0 = *(const bf16x8*)&Blg[0], pl1 = *(const bf16x8*)&Blg[32];

  for (int k0 = 0; k0 < 1024; k0 += 64) {
    __syncthreads();
    *(bf16x8*)&Ah[sr * 72 + c8] = pa0;  *(bf16x8*)&Ah[sr * 72 + c8 + 32] = pa1;
    *(bf16x8*)&Al[sr * 72 + c8] = pc0;  *(bf16x8*)&Al[sr * 72 + c8 + 32] = pc1;
    *(bf16x8*)&Bh[sr * 72 + c8] = pb0;  *(bf16x8*)&Bh[sr * 72 + c8 + 32] = pb1;
    *(bf16x8*)&Bl[sr * 72 + c8] = pl0;  *(bf16x8*)&Bl[sr * 72 + c8 + 32] = pl1;
    if (k0 + 64 < 1024) {
      const size_t an = abase + (size_t)((k0 >> 6) + 1) * 262144;
      pa0 = *(const bf16x8*)&AOhi[an]; pa1 = *(const bf16x8*)&AOhi[an + 32];
      pc0 = *(const bf16x8*)&AOlo[an]; pc1 = *(const bf16x8*)&AOlo[an + 32];
      pb0 = *(const bf16x8*)&Bhg[k0 + 64]; pb1 = *(const bf16x8*)&Bhg[k0 + 96];
      pl0 = *(const bf16x8*)&Blg[k0 + 64]; pl1 = *(const bf16x8*)&Blg[k0 + 96];
    }
    __syncthreads();
#pragma unroll
    for (int kh = 0; kh < 2; kh++) {
      const int ko = kh * 32 + lg * 8;
      bf16x8 bh0 = *(const bf16x8*)&Bh[(wc * 32 + lq) * 72 + ko];
      bf16x8 bh1 = *(const bf16x8*)&Bh[(wc * 32 + 16 + lq) * 72 + ko];
      bf16x8 bl0 = *(const bf16x8*)&Bl[(wc * 32 + lq) * 72 + ko];
      bf16x8 bl1 = *(const bf16x8*)&Bl[(wc * 32 + 16 + lq) * 72 + ko];
#pragma unroll
      for (int i = 0; i < 2; i++) {
        bf16x8 ahv = *(const bf16x8*)&Ah[(wr * 32 + i * 16 + lq) * 72 + ko];
        bf16x8 alv = *(const bf16x8*)&Al[(wr * 32 + i * 16 + lq) * 72 + ko];
        acc[i][0] = MFMA16(ahv, bh0, acc[i][0]);
        acc[i][0] = MFMA16(alv, bh0, acc[i][0]);
        acc[i][0] = MFMA16(ahv, bl0, acc[i][0]);
        acc[i][1] = MFMA16(ahv, bh1, acc[i][1]);
        acc[i][1] = MFMA16(alv, bh1, acc[i][1]);
        acc[i][1] = MFMA16(ahv, bl1, acc[i][1]);
      }
    }
  }

#pragma unroll
  for (int i = 0; i < 2; i++)
#pragma unroll
    for (int j = 0; j < 2; j++)
#pragma unroll
      for (int ri = 0; ri < 4; ri++) {
        int m = m0 + wr * 32 + i * 16 + 4 * lg + ri;
        int e = n0 + wc * 32 + j * 16 + lq;
        out[(size_t)m * 1024 + e] = acc[i][j][ri] + bias[e];
      }
}

// scan a packed-u16 256-bin hist row for the bin containing rank `target`.
// RANKMAP=true: hist is indexed by RAW fp16 top-8 bits; traverse in
// decreasing-VALUE order (raw 0x7F..0x00 then 0x80..0xFF). Output bin is a
// RANK in 0..255. RANKMAP=false: hist already rank-ordered.
template <bool RANKMAP>
__device__ __forceinline__ void scan_row(const unsigned* hrow, unsigned target,
                                         int lane, int* binOut, unsigned* remOut) {
  unsigned c0, c1, c2, c3;
  if (RANKMAP) {
    const bool neg = lane >= 32;
    const int ho = neg ? (lane << 1) : (62 - (lane << 1));
    uint2 hw = *(const uint2*)&hrow[ho];
    unsigned a0 = hw.x & 0xffffu, a1 = hw.x >> 16;
    unsigned a2 = hw.y & 0xffffu, a3 = hw.y >> 16;
    c0 = neg ? a0 : a3; c1 = neg ? a1 : a2;
    c2 = neg ? a2 : a1; c3 = neg ? a3 : a0;
  } else {
    uint2 hw = *(const uint2*)&hrow[lane << 1];
    c0 = hw.x & 0xffffu; c1 = hw.x >> 16;
    c2 = hw.y & 0xffffu; c3 = hw.y >> 16;
  }
  unsigned s4 = c0 + c1 + c2 + c3, incl = s4;
#pragma unroll
  for (int off = 1; off < 64; off <<= 1) {
    unsigned t = __shfl_up(incl, off);
    if (lane >= off) incl += t;
  }
  unsigned excl = incl - s4;
  bool found = (excl < target) && (target <= incl);
  int b = 0; unsigned rm = 1;
  if (found) {
    unsigned cum = excl;
    if (cum + c0 >= target) { b = (lane << 2); rm = target - cum; }
    else { cum += c0;
      if (cum + c1 >= target) { b = (lane << 2) + 1; rm = target - cum; }
      else { cum += c1;
        if (cum + c2 >= target) { b = (lane << 2) + 2; rm = target - cum; }
        else { cum += c2; b = (lane << 2) + 3; rm = target - cum; } } }
  }
  unsigned long long bal = __ballot(found);
  int src = (int)__builtin_ctzll(bal);
  *binOut = __shfl(b, src);
  *remOut = (unsigned)__shfl((int)rm, src);
}

// ---- P1 macros: fp16 K frag loads (per-lane base + const offsets) ----
#define KLOAD(F, gg)                                                   \
  do {                                                                 \
    _Pragma("unroll") for (int tt = 0; tt < 4; tt++) {                 \
      const int koff = ((gg) * 4 + tt) * 1024;                         \
      F[tt * 2 + 0] = *(const f16x8*)&kbase[koff];                     \
      F[tt * 2 + 1] = *(const f16x8*)&kbase[koff + 32];                \
    }                                                                  \
  } while (0)

// C = K·Q^T -> C[row=s_loc=4lg+ri][col=q=lq]; fp16 score + RAW top-8 hist
// (rank mapping deferred to P2's scan — no key math per score)
#define KCOMP(F, gg)                                                          \
  do {                                                                        \
    _Pragma("unroll") for (int tt = 0; tt < 4; tt++) {                        \
      f32x4 acc_ = {0.f, 0.f, 0.f, 0.f};                                      \
      acc_ = MFMAH16(F[tt * 2 + 0], qf0, acc_);                               \
      acc_ = MFMAH16(F[tt * 2 + 1], qf1, acc_);                               \
      uint2 pw_;                                                              \
      pw_.x = (unsigned)f2h(acc_[0]) | ((unsigned)f2h(acc_[1]) << 16);        \
      pw_.y = (unsigned)f2h(acc_[2]) | ((unsigned)f2h(acc_[3]) << 16);        \
      atomicAdd(&histP[lq * HSTR + ((pw_.x >> 9) & 0x7Fu)],                   \
                1u << (((pw_.x >> 8) & 1u) << 4));                            \
      atomicAdd(&histP[lq * HSTR + (pw_.x >> 25)],                            \
                1u << (((pw_.x >> 24) & 1u) << 4));                           \
      atomicAdd(&histP[lq * HSTR + ((pw_.y >> 9) & 0x7Fu)],                   \
                1u << (((pw_.y >> 8) & 1u) << 4));                            \
      atomicAdd(&histP[lq * HSTR + (pw_.y >> 25)],                            \
                1u << (((pw_.y >> 24) & 1u) << 4));                           \
      const int st_ = (w * 16 + (gg) * 4 + tt) * 16;                          \
      *(uint2*)&scH[lq * SROW + ((st_ + 4 * lg) ^ xr8q)] = pw_;               \
    }                                                                         \
  } while (0)

// One WG = 512 thr (8 waves) per (n, h, 16 q-rows). 76.6 KB LDS => 2 WG/CU,
// 16 waves/CU (4/SIMD). Two independent WGs interleave across barriers.
__global__ __launch_bounds__(512, 2) void sparse_attn(
    const ushort_t* __restrict__ Qf, const ushort_t* __restrict__ Kfp,
    const ushort_t* __restrict__ Vt, ushort_t* __restrict__ AOhi,
    ushort_t* __restrict__ AOlo) {
  __shared__ ushort_t scH[16 * SROW];   // 65536 B fp16 scores, then fp16 P
  __shared__ unsigned histP[16 * HSTR]; // 8448 B packed u16x2 counts (RAW bins)
  __shared__ float Obuf[16 * 68];       // 4352 B partial O [q][d]
  __shared__ float dinvS[16];

  // bijective XCD swizzle: each XCD owns a contiguous 512-block range
  const int flat = blockIdx.x + 128 * (blockIdx.y + 16 * blockIdx.z);
  const int idx = (flat & 7) * 512 + (flat >> 3);
  const int lb = idx & 127, h = (idx >> 7) & 15, n = idx >> 11;

  const int tid = threadIdx.x;
  const int lane = tid & 63, w = tid >> 6;  // w 0..7
  const int lg = lane >> 4, lq = lane & 15;
  const int xr8q = (lq & 7) << 3;
  const size_t nh = (size_t)(n * 16 + h);

  for (int i = tid; i < 16 * HSTR; i += 512) histP[i] = 0u;
  for (int i = tid; i < 16 * 68; i += 512) Obuf[i] = 0.f;

  // Q frags (fp16, pre-scaled incl. log2e): B-operand B[k=d][c=q=lq]
  const size_t qo = (nh * 2048 + (size_t)lb * 16 + lq) * 64 + lg * 8;
  const f16x8 qf0 = *(const f16x8*)&Qf[qo];
  const f16x8 qf1 = *(const f16x8*)&Qf[qo + 32];

  const ushort_t* Kf = Kfp + nh * 2048 * 64;
  const ushort_t* kbase = Kf + (size_t)(w * 256 + lq) * 64 + lg * 8;

  // first K-group issued BEFORE the zero-barrier (overlaps LDS zeroing)
  f16x8 fa[8], fb[8];
  KLOAD(fa, 0);

  __syncthreads();  // hist + Obuf zeroed

  // ---------------- Phase 1: 16 s-tiles per wave ----------------
  {
    for (int g = 0; g < 4; g += 2) {
      KLOAD(fb, g + 1);
      KCOMP(fa, g);
      if (g + 2 < 4) KLOAD(fa, g + 2);
      KCOMP(fb, g + 1);
    }
  }
  __syncthreads();  // scores + hist complete

  // ---- P3 V-quad prefetch (global, independent of P2) ----
  const int db3 = w & 3, sh3 = w >> 2;
  const int sOff3 = sh3 * 1024;
  const ushort_t* Vb = Vt + (nh * 64 + (size_t)(db3 * 16 + lq)) * 2048 + sOff3;
  f16x8 pv0 = *(const f16x8*)&Vb[lg * 8];
  f16x8 pv1 = *(const f16x8*)&Vb[32 + lg * 8];
  f16x8 pv2 = *(const f16x8*)&Vb[64 + lg * 8];
  f16x8 pv3 = *(const f16x8*)&Vb[96 + lg * 8];

  // ---------------- Phase 2: rows 2w, 2w+1 ----------------
  for (int rr = 0; rr < 2; rr++) {
    const int r = w * 2 + rr;
    const int rb = r * SROW;
    const int xr = (r & 7) << 3;
    unsigned* hrow = &histP[r * HSTR];

    int b1r; unsigned rem;
    scan_row<true>(hrow, KSEL, lane, &b1r, &rem);
    // rank bin -> raw top-8 bin; sub-byte rank xor (pos: desc, neg: asc)
    const unsigned rb1 = (b1r < 128) ? (unsigned)(b1r ^ 0x7F) : (unsigned)b1r;
    const unsigned sxor = (rb1 & 0x80u) ? 0u : 0xFFu;

    // read this lane's 32 scores ONCE
    uint4 rv0 = *(const uint4*)&scH[rb + ((0 * 512 + lane * 8) ^ xr)];
    uint4 rv1 = *(const uint4*)&scH[rb + ((1 * 512 + lane * 8) ^ xr)];
    uint4 rv2 = *(const uint4*)&scH[rb + ((2 * 512 + lane * 8) ^ xr)];
    uint4 rv3 = *(const uint4*)&scH[rb + ((3 * 512 + lane * 8) ^ xr)];

    // refine within raw bin rb1 (sub-bins stored rank-ordered), from regs
    *(uint2*)&hrow[lane << 1] = make_uint2(0u, 0u);
    __threadfence_block();
    auto refine1 = [&](unsigned wd) {
      if (((wd >> 8) & 0xFFu) == rb1) {
        unsigned sr_ = (wd & 0xFFu) ^ sxor;
        atomicAdd(&hrow[sr_ >> 1], 1u << ((sr_ & 1u) << 4));
      }
      if ((wd >> 24) == rb1) {
        unsigned sr_ = ((wd >> 16) & 0xFFu) ^ sxor;
        atomicAdd(&hrow[sr_ >> 1], 1u << ((sr_ & 1u) << 4));
      }
    };
    refine1(rv0.x); refine1(rv0.y); refine1(rv0.z); refine1(rv0.w);
    refine1(rv1.x); refine1(rv1.y); refine1(rv1.z); refine1(rv1.w);
    refine1(rv2.x); refine1(rv2.y); refine1(rv2.z); refine1(rv2.w);
    refine1(rv3.x); refine1(rv3.y); refine1(rv3.z); refine1(rv3.w);
    __threadfence_block();
    int b2r; unsigned rem2;
    scan_row<false>(hrow, rem, lane, &b2r, &rem2);
    (void)rem2;
    // exact fp16 threshold value: keep iff score >= fV
    const unsigned vbits = (rb1 << 8) | (((unsigned)b2r) ^ sxor);
    const float fV = h2f((ushort_t)vbits);

    // exp2 from registers (scores pre-scaled by log2e): fp16 P in place
    float den = 0.f;
    auto exp2w = [&](unsigned wd) -> unsigned {
      float f0 = h2f((ushort_t)(wd & 0xffffu));
      float f1 = h2f((ushort_t)(wd >> 16));
      float e0 = (f0 >= fV) ? __builtin_amdgcn_exp2f(f0) : 0.f;
      float e1 = (f1 >= fV) ? __builtin_amdgcn_exp2f(f1) : 0.f;
      den += e0 + e1;
      return (unsigned)f2h(e0) | ((unsigned)f2h(e1) << 16);
    };
    uint4 ov;
    ov.x = exp2w(rv0.x); ov.y = exp2w(rv0.y); ov.z = exp2w(rv0.z); ov.w = exp2w(rv0.w);
    *(uint4*)&scH[rb + ((0 * 512 + lane * 8) ^ xr)] = ov;
    ov.x = exp2w(rv1.x); ov.y = exp2w(rv1.y); ov.z = exp2w(rv1.z); ov.w = exp2w(rv1.w);
    *(uint4*)&scH[rb + ((1 * 512 + lane * 8) ^ xr)] = ov;
    ov.x = exp2w(rv2.x); ov.y = exp2w(rv2.y); ov.z = exp2w(rv2.z); ov.w = exp2w(rv2.w);
    *(uint4*)&scH[rb + ((2 * 512 + lane * 8) ^ xr)] = ov;
    ov.x = exp2w(rv3.x); ov.y = exp2w(rv3.y); ov.z = exp2w(rv3.z); ov.w = exp2w(rv3.w);
    *(uint4*)&scH[rb + ((3 * 512 + lane * 8) ^ xr)] = ov;

#pragma unroll
    for (int off = 32; off > 0; off >>= 1) den += __shfl_xor(den, off);
    if (lane == 0) dinvS[r] = 1.0f / den;
  }
  __syncthreads();  // P + dinvS ready

  // ---- Phase 3: PV quadrant (d-block w&3, s-half w>>2), 3-deep prefetch ----
  {
    const int xw = (lq & 7) << 3;
    const int arow = lq * SROW;
    f32x4 o0 = {0.f, 0.f, 0.f, 0.f}, o1 = o0, o2 = o0, o3 = o0;
    f16x8 va0 = pv0, va1 = pv1, vb0 = pv2, vb1 = pv3;
#pragma unroll 2
    for (int c = 0; c < 16; c += 2) {
      f16x8 na0, na1, nb0, nb1;
      if (c + 2 < 16) {
        na0 = *(const f16x8*)&Vb[(c + 2) * 64 + lg * 8];
        na1 = *(const f16x8*)&Vb[(c + 2) * 64 + 32 + lg * 8];
        nb0 = *(const f16x8*)&Vb[(c + 3) * 64 + lg * 8];
        nb1 = *(const f16x8*)&Vb[(c + 3) * 64 + 32 + lg * 8];
      }
      f16x8 pa0 = *(const f16x8*)&scH[arow + ((sOff3 + c * 64 + lg * 8) ^ xw)];
      f16x8 pa1 = *(const f16x8*)&scH[arow + ((sOff3 + c * 64 + 32 + lg * 8) ^ xw)];
      o0 = MFMAH16(pa0, va0, o0);
      o1 = MFMAH16(pa1, va1, o1);
      f16x8 pb0_ = *(const f16x8*)&scH[arow + ((sOff3 + (c + 1) * 64 + lg * 8) ^ xw)];
      f16x8 pb1_ = *(const f16x8*)&scH[arow + ((sOff3 + (c + 1) * 64 + 32 + lg * 8) ^ xw)];
      o2 = MFMAH16(pb0_, vb0, o2);
      o3 = MFMAH16(pb1_, vb1, o3);
      va0 = na0; va1 = na1; vb0 = nb0; vb1 = nb1;
    }
    f32x4 oa = (o0 + o1) + (o2 + o3);
#pragma unroll
    for (int ri = 0; ri < 4; ri++) {
      int q = lg * 4 + ri;
      atomicAdd(&Obuf[q * 68 + db3 * 16 + lq], oa[ri]);
    }
  }
  __syncthreads();  // partial O combined

  // ---- epilogue: scale by 1/den, write AO2[h][m][d] (line-dense) ----
  {
#pragma unroll
    for (int rep = 0; rep < 2; rep++) {
      int idx2 = tid + rep * 512;
      int q = idx2 >> 6, d = idx2 & 63;
      float val = Obuf[q * 68 + d] * dinvS[q];
      size_t ai = ((size_t)h * 4096 + (size_t)(lb * 16 + q) * 2 + n) * 64 +
                  (size_t)d;
      ushort_t hb = f2bf(val);
      AOhi[ai] = hb;
      AOlo[ai] = f2bf(val - bf2f(hb));
    }
  }
}

extern "C" void kernel_launch(void* const* d_in, const int* in_sizes, int n_in,
                              void* d_out, int out_size, void* d_ws, size_t ws_size,
                              hipStream_t stream) {
  const float* query = (const float*)d_in[0];
  const float* key   = (const float*)d_in[1];
  const float* value = (const float*)d_in[2];
  const float* Wq    = (const float*)d_in[3];
  const float* bq    = (const float*)d_in[4];
  const float* Wk    = (const float*)d_in[5];
  const float* bk    = (const float*)d_in[6];
  const float* Wv    = (const float*)d_in[7];
  const float* bv    = (const float*)d_in[8];
  const float* Wo    = (const float*)d_in[9];
  const float* bo    = (const float*)d_in[10];

  ushort_t* Qf   = (ushort_t*)d_ws;
  ushort_t* Kf   = Qf + 4194304;
  ushort_t* Vt   = Kf + 4194304;
  ushort_t* AOhi = Vt + 4194304;
  ushort_t* AOlo = AOhi + 4194304;
  ushort_t* Whi  = AOlo + 4194304;
  ushort_t* Wlo  = Whi + 4194304;

  dim3 block(256);
  presplit_w<<<dim3(512, 4), block, 0, stream>>>(Wq, Wk, Wv, Wo, Whi, Wlo);

  proj_qkv<<<dim3(8, 64, 3), block, 0, stream>>>(query, key, value, bq, bk, bv,
                                                 Whi, Qf, Kf, Vt);

  sparse_attn<<<dim3(128, 16, 2), dim3(512), 0, stream>>>(Qf, Kf, Vt, AOhi, AOlo);

  proj_out<<<dim3(16, 64), block, 0, stream>>>(AOhi, AOlo, Whi + 3 * 1048576,
                                               Wlo + 3 * 1048576, bo,
                                               (float*)d_out);
}

// Round 6
// 356.937 us; speedup vs baseline: 1.0722x; 1.0675x over previous
//
#include <hip/hip_runtime.h>
#include <hip/hip_bf16.h>
#include <hip/hip_fp16.h>

// MultiHeadSparseAttention. R23 = R20 sparse_attn byte-exact (268us attn;
// R21/R22 proved ANY source-level reordering of P1/P2/P3 costs ~25us —
// schedule-fragile local optimum, do not touch) + proj_out widened to
// 64x128 N-tiles (mirrors R20's proven proj_qkv widen: halves AO-panel
// re-reads 16->8 passes, doubles MFMA density 24->48 per k-step per wave;
// LDS 55.3KB -> 2 WG/CU). Math identical everywhere.
//   P1: wave w -> 16 s-tiles (s in [w*256, w*256+256))
//   P2: wave w -> rows 2w, 2w+1 (scan + refine + exp pass, per-row)
//   P3: wave w -> (d-block w&3, s-half w>>2); f32-atomic combine in Obuf
// L=S=2048, N=2, E=1024, H=16, D=64, k_sel = int(2048*sigmoid(0.3)) = 1176.
//
// ws (halfwords): Qf 4M | Kf 4M | Vt 4M | AOhi 4M | AOlo 4M | Whi 4M | Wlo 4M

#define KSEL 1176u
#define SROW 2048  // fp16 score row stride (elements) — bank-aligned rows
#define HSTR 132   // hist row stride in u32

typedef __attribute__((ext_vector_type(8))) short bf16x8;
typedef __attribute__((ext_vector_type(8))) _Float16 f16x8;
typedef __attribute__((ext_vector_type(4))) float f32x4;
typedef unsigned short ushort_t;

union S8 { bf16x8 v; ushort_t u[8]; };
union H8 { f16x8 v; ushort_t u[8]; };

#define MFMA16(A, B, C)  __builtin_amdgcn_mfma_f32_16x16x32_bf16(A, B, C, 0, 0, 0)
#define MFMAH16(A, B, C) __builtin_amdgcn_mfma_f32_16x16x32_f16(A, B, C, 0, 0, 0)

__device__ __forceinline__ ushort_t f2bf(float x) {  // RNE f32->bf16
  unsigned u = __float_as_uint(x);
  return (ushort_t)((u + 0x7FFFu + ((u >> 16) & 1u)) >> 16);
}
__device__ __forceinline__ float bf2f(ushort_t b) {
  return __uint_as_float(((unsigned)b) << 16);
}
__device__ __forceinline__ ushort_t f2h(float x) {
  return __half_as_ushort(__float2half(x));
}
__device__ __forceinline__ float h2f(ushort_t b) {
  return __half2float(__ushort_as_half(b));
}

// convert 8 fp32 (two float4) to fp16, store as f16x8
__device__ __forceinline__ void cvt8(ushort_t* dst, float4 p, float4 q) {
  H8 t;
  t.u[0] = f2h(p.x); t.u[1] = f2h(p.y); t.u[2] = f2h(p.z); t.u[3] = f2h(p.w);
  t.u[4] = f2h(q.x); t.u[5] = f2h(q.y); t.u[6] = f2h(q.z); t.u[7] = f2h(q.w);
  *(f16x8*)dst = t.v;
}

// ---- W prep: Wq/Wk/Wv -> fp16 (Whi only); Wo -> bf16 hi/lo PERMUTED ----
__global__ __launch_bounds__(256) void presplit_w(
    const float* __restrict__ W0, const float* __restrict__ W1,
    const float* __restrict__ W2, const float* __restrict__ W3,
    ushort_t* __restrict__ Whi, ushort_t* __restrict__ Wlo) {
  const int m = blockIdx.y;
  const float* W = (m == 0) ? W0 : (m == 1) ? W1 : (m == 2) ? W2 : W3;
  const size_t off = ((size_t)blockIdx.x * 256 + threadIdx.x) * 8;
  const size_t base = (size_t)m * 1048576 + off;
  if (m == 3) {
    const int f = (int)(off >> 10);
    const int r = (int)(off & 1023);
    const int hcol = r >> 6, d0 = r & 63;
    S8 hi_, lo_;
#pragma unroll
    for (int j = 0; j < 8; j++) {
      float x = W[(size_t)f * 1024 + (size_t)(d0 + j) * 16 + hcol];
      ushort_t hb = f2bf(x);
      hi_.u[j] = hb;
      lo_.u[j] = f2bf(x - bf2f(hb));
    }
    *(bf16x8*)&Whi[base] = hi_.v;
    *(bf16x8*)&Wlo[base] = lo_.v;
  } else {
    float4 p = *(const float4*)&W[off];
    float4 q = *(const float4*)&W[off + 4];
    cvt8(&Whi[base], p, q);
  }
}

// -------- fused Q/K/V projection: 64x128 tile, plain fp16, 1 MFMA --------
__global__ __launch_bounds__(256, 4) void proj_qkv(
    const float* __restrict__ Xq, const float* __restrict__ Xk,
    const float* __restrict__ Xv, const float* __restrict__ bq,
    const float* __restrict__ bk, const float* __restrict__ bv,
    const ushort_t* __restrict__ Whi, ushort_t* __restrict__ Qf,
    ushort_t* __restrict__ Kf, ushort_t* __restrict__ Vt) {
  __shared__ ushort_t Ah[64 * 72], Bh[128 * 72];
  const int z = blockIdx.z;
  const float* X = (z == 0) ? Xq : (z == 1) ? Xk : Xv;
  const float* bias = (z == 0) ? bq : (z == 1) ? bk : bv;
  const size_t zoff = (size_t)z * 1048576;

  const int tid = threadIdx.x;
  const int n0 = blockIdx.x * 128, m0 = blockIdx.y * 64;
  const int lane = tid & 63, wv = tid >> 6;
  const int lg = lane >> 4, lq = lane & 15;
  const int wr = wv >> 1, wc = wv & 1;
  const int sr = tid >> 2, c8 = (tid & 3) * 8;

  f32x4 acc[2][4] = {};

  const float* Xr = &X[(size_t)(m0 + sr) * 1024 + c8];
  const ushort_t* Bg0 = Whi + zoff + (size_t)(n0 + sr) * 1024 + c8;
  const ushort_t* Bg1 = Bg0 + 64 * 1024;

  float4 a0 = *(const float4*)&Xr[0],  a1 = *(const float4*)&Xr[4];
  float4 a2 = *(const float4*)&Xr[32], a3 = *(const float4*)&Xr[36];
  f16x8 pb0 = *(const f16x8*)&Bg0[0], pb1 = *(const f16x8*)&Bg0[32];
  f16x8 pb2 = *(const f16x8*)&Bg1[0], pb3 = *(const f16x8*)&Bg1[32];

  for (int k0 = 0; k0 < 1024; k0 += 64) {
    __syncthreads();
    cvt8(&Ah[sr * 72 + c8], a0, a1);
    cvt8(&Ah[sr * 72 + c8 + 32], a2, a3);
    *(f16x8*)&Bh[sr * 72 + c8] = pb0;
    *(f16x8*)&Bh[sr * 72 + c8 + 32] = pb1;
    *(f16x8*)&Bh[(64 + sr) * 72 + c8] = pb2;
    *(f16x8*)&Bh[(64 + sr) * 72 + c8 + 32] = pb3;
    if (k0 + 64 < 1024) {
      const float* Xn = Xr + k0 + 64;
      a0 = *(const float4*)&Xn[0];  a1 = *(const float4*)&Xn[4];
      a2 = *(const float4*)&Xn[32]; a3 = *(const float4*)&Xn[36];
      pb0 = *(const f16x8*)&Bg0[k0 + 64];
      pb1 = *(const f16x8*)&Bg0[k0 + 96];
      pb2 = *(const f16x8*)&Bg1[k0 + 64];
      pb3 = *(const f16x8*)&Bg1[k0 + 96];
    }
    __syncthreads();
#pragma unroll
    for (int kh = 0; kh < 2; kh++) {
      const int ko = kh * 32 + lg * 8;
      f16x8 bh0 = *(const f16x8*)&Bh[(wc * 64 + lq) * 72 + ko];
      f16x8 bh1 = *(const f16x8*)&Bh[(wc * 64 + 16 + lq) * 72 + ko];
      f16x8 bh2 = *(const f16x8*)&Bh[(wc * 64 + 32 + lq) * 72 + ko];
      f16x8 bh3 = *(const f16x8*)&Bh[(wc * 64 + 48 + lq) * 72 + ko];
#pragma unroll
      for (int i = 0; i < 2; i++) {
        f16x8 ahv = *(const f16x8*)&Ah[(wr * 32 + i * 16 + lq) * 72 + ko];
        acc[i][0] = MFMAH16(ahv, bh0, acc[i][0]);
        acc[i][1] = MFMAH16(ahv, bh1, acc[i][1]);
        acc[i][2] = MFMAH16(ahv, bh2, acc[i][2]);
        acc[i][3] = MFMAH16(ahv, bh3, acc[i][3]);
      }
    }
  }

  ushort_t* dqk = (z == 0) ? Qf : Kf;
#pragma unroll
  for (int i = 0; i < 2; i++)
#pragma unroll
    for (int j = 0; j < 4; j++)
#pragma unroll
      for (int ri = 0; ri < 4; ri++) {
        int m = m0 + wr * 32 + i * 16 + 4 * lg + ri;
        int e = n0 + wc * 64 + j * 16 + lq;
        float v = acc[i][j][ri] + bias[e];
        int l = m >> 1, n = m & 1, hh = e >> 6, d = e & 63;
        if (z == 2) {
          Vt[((size_t)(n * 16 + hh) * 64 + d) * 2048 + l] = f2h(v);
        } else {
          // Q scale = 1/sqrt(64) * log2(e): scores land in exp2 domain
          float x = (z == 0) ? v * (0.125f * 1.4426950408889634f) : v;
          dqk[((size_t)(n * 16 + hh) * 2048 + l) * 64 + d] = f2h(x);
        }
      }
}

// --- output projection: 64x128 tile; A = AO2[h][m][d] hi/lo, B = WoP ---
__global__ __launch_bounds__(256, 2) void proj_out(
    const ushort_t* __restrict__ AOhi, const ushort_t* __restrict__ AOlo,
    const ushort_t* __restrict__ Whi3, const ushort_t* __restrict__ Wlo3,
    const float* __restrict__ bias, float* __restrict__ out) {
  __shared__ ushort_t Ah[64 * 72], Al[64 * 72], Bh[128 * 72], Bl[128 * 72];
  const int tid = threadIdx.x;
  const int n0 = blockIdx.x * 128, m0 = blockIdx.y * 64;
  const int lane = tid & 63, wv = tid >> 6;
  const int lg = lane >> 4, lq = lane & 15;
  const int wr = wv >> 1, wc = wv & 1;
  const int sr = tid >> 2, c8 = (tid & 3) * 8;

  f32x4 acc[2][4] = {};

  const size_t abase = (size_t)(m0 + sr) * 64 + c8;
  const ushort_t* Bg0 = Whi3 + (size_t)(n0 + sr) * 1024 + c8;
  const ushort_t* Bg1 = Bg0 + 64 * 1024;
  const ushort_t* Lg0 = Wlo3 + (size_t)(n0 + sr) * 1024 + c8;
  const ushort_t* Lg1 = Lg0 + 64 * 1024;

  bf16x8 pa0 = *(const bf16x8*)&AOhi[abase], pa1 = *(const bf16x8*)&AOhi[abase + 32];
  bf16x8 pc0 = *(const bf16x8*)&AOlo[abase], pc1 = *(const bf16x8*)&AOlo[abase + 32];
  bf16x8 pb0 = *(const bf16x8*)&Bg0[0], pb1 = *(const bf16x8*)&Bg0[32];
  bf16x8 pb2 = *(const bf16x8*)&Bg1[0], pb3 = *(const bf16x8*)&Bg1[32];
  bf16x8 pl0 = *(const bf16x8*)&Lg0[0], pl1 = *(const bf16x8*)&Lg0[32];
  bf16x8 pl2 = *(const bf16x8*)&Lg1[0], pl3 = *(const bf16x8*)&Lg1[32];

  for (int k0 = 0; k0 < 1024; k0 += 64) {
    __syncthreads();
    *(bf16x8*)&Ah[sr * 72 + c8] = pa0;  *(bf16x8*)&Ah[sr * 72 + c8 + 32] = pa1;
    *(bf16x8*)&Al[sr * 72 + c8] = pc0;  *(bf16x8*)&Al[sr * 72 + c8 + 32] = pc1;
    *(bf16x8*)&Bh[sr * 72 + c8] = pb0;  *(bf16x8*)&Bh[sr * 72 + c8 + 32] = pb1;
    *(bf16x8*)&Bh[(64 + sr) * 72 + c8] = pb2;
    *(bf16x8*)&Bh[(64 + sr) * 72 + c8 + 32] = pb3;
    *(bf16x8*)&Bl[sr * 72 + c8] = pl0;  *(bf16x8*)&Bl[sr * 72 + c8 + 32] = pl1;
    *(bf16x8*)&Bl[(64 + sr) * 72 + c8] = pl2;
    *(bf16x8*)&Bl[(64 + sr) * 72 + c8 + 32] = pl3;
    if (k0 + 64 < 1024) {
      const size_t an = abase + (size_t)((k0 >> 6) + 1) * 262144;
      pa0 = *(const bf16x8*)&AOhi[an]; pa1 = *(const bf16x8*)&AOhi[an + 32];
      pc0 = *(const bf16x8*)&AOlo[an]; pc1 = *(const bf16x8*)&AOlo[an + 32];
      pb0 = *(const bf16x8*)&Bg0[k0 + 64]; pb1 = *(const bf16x8*)&Bg0[k0 + 96];
      pb2 = *(const bf16x8*)&Bg1[k0 + 64]; pb3 = *(const bf16x8*)&Bg1[k0 + 96];
      pl0 = *(const bf16x8*)&Lg0[k0 + 64]; pl1 = *(const bf16x8*)&Lg0[k0 + 96];
      pl2 = *(const bf16x8*)&Lg1[k0 + 64]; pl3 = *(const bf16x8*)&Lg1[k0 + 96];
    }
    __syncthreads();
#pragma unroll
    for (int kh = 0; kh < 2; kh++) {
      const int ko = kh * 32 + lg * 8;
#pragma unroll
      for (int i = 0; i < 2; i++) {
        bf16x8 ahv = *(const bf16x8*)&Ah[(wr * 32 + i * 16 + lq) * 72 + ko];
        bf16x8 alv = *(const bf16x8*)&Al[(wr * 32 + i * 16 + lq) * 72 + ko];
#pragma unroll
        for (int j = 0; j < 4; j++) {
          bf16x8 bhv = *(const bf16x8*)&Bh[(wc * 64 + j * 16 + lq) * 72 + ko];
          bf16x8 blv = *(const bf16x8*)&Bl[(wc * 64 + j * 16 + lq) * 72 + ko];
          acc[i][j] = MFMA16(ahv, bhv, acc[i][j]);
          acc[i][j] = MFMA16(alv, bhv, acc[i][j]);
          acc[i][j] = MFMA16(ahv, blv, acc[i][j]);
        }
      }
    }
  }

#pragma unroll
  for (int i = 0; i < 2; i++)
#pragma unroll
    for (int j = 0; j < 4; j++)
#pragma unroll
      for (int ri = 0; ri < 4; ri++) {
        int m = m0 + wr * 32 + i * 16 + 4 * lg + ri;
        int e = n0 + wc * 64 + j * 16 + lq;
        out[(size_t)m * 1024 + e] = acc[i][j][ri] + bias[e];
      }
}

// scan a packed-u16 256-bin hist row for the bin containing rank `target`.
// RANKMAP=true: hist is indexed by RAW fp16 top-8 bits; traverse in
// decreasing-VALUE order (raw 0x7F..0x00 then 0x80..0xFF). Output bin is a
// RANK in 0..255. RANKMAP=false: hist already rank-ordered.
template <bool RANKMAP>
__device__ __forceinline__ void scan_row(const unsigned* hrow, unsigned target,
                                         int lane, int* binOut, unsigned* remOut) {
  unsigned c0, c1, c2, c3;
  if (RANKMAP) {
    const bool neg = lane >= 32;
    const int ho = neg ? (lane << 1) : (62 - (lane << 1));
    uint2 hw = *(const uint2*)&hrow[ho];
    unsigned a0 = hw.x & 0xffffu, a1 = hw.x >> 16;
    unsigned a2 = hw.y & 0xffffu, a3 = hw.y >> 16;
    c0 = neg ? a0 : a3; c1 = neg ? a1 : a2;
    c2 = neg ? a2 : a1; c3 = neg ? a3 : a0;
  } else {
    uint2 hw = *(const uint2*)&hrow[lane << 1];
    c0 = hw.x & 0xffffu; c1 = hw.x >> 16;
    c2 = hw.y & 0xffffu; c3 = hw.y >> 16;
  }
  unsigned s4 = c0 + c1 + c2 + c3, incl = s4;
#pragma unroll
  for (int off = 1; off < 64; off <<= 1) {
    unsigned t = __shfl_up(incl, off);
    if (lane >= off) incl += t;
  }
  unsigned excl = incl - s4;
  bool found = (excl < target) && (target <= incl);
  int b = 0; unsigned rm = 1;
  if (found) {
    unsigned cum = excl;
    if (cum + c0 >= target) { b = (lane << 2); rm = target - cum; }
    else { cum += c0;
      if (cum + c1 >= target) { b = (lane << 2) + 1; rm = target - cum; }
      else { cum += c1;
        if (cum + c2 >= target) { b = (lane << 2) + 2; rm = target - cum; }
        else { cum += c2; b = (lane << 2) + 3; rm = target - cum; } } }
  }
  unsigned long long bal = __ballot(found);
  int src = (int)__builtin_ctzll(bal);
  *binOut = __shfl(b, src);
  *remOut = (unsigned)__shfl((int)rm, src);
}

// ---- P1 macros: fp16 K frag loads (per-lane base + const offsets) ----
#define KLOAD(F, gg)                                                   \
  do {                                                                 \
    _Pragma("unroll") for (int tt = 0; tt < 4; tt++) {                 \
      const int koff = ((gg) * 4 + tt) * 1024;                         \
      F[tt * 2 + 0] = *(const f16x8*)&kbase[koff];                     \
      F[tt * 2 + 1] = *(const f16x8*)&kbase[koff + 32];                \
    }                                                                  \
  } while (0)

// C = K·Q^T -> C[row=s_loc=4lg+ri][col=q=lq]; fp16 score + RAW top-8 hist
// (rank mapping deferred to P2's scan — no key math per score)
#define KCOMP(F, gg)                                                          \
  do {                                                                        \
    _Pragma("unroll") for (int tt = 0; tt < 4; tt++) {                        \
      f32x4 acc_ = {0.f, 0.f, 0.f, 0.f};                                      \
      acc_ = MFMAH16(F[tt * 2 + 0], qf0, acc_);                               \
      acc_ = MFMAH16(F[tt * 2 + 1], qf1, acc_);                               \
      uint2 pw_;                                                              \
      pw_.x = (unsigned)f2h(acc_[0]) | ((unsigned)f2h(acc_[1]) << 16);        \
      pw_.y = (unsigned)f2h(acc_[2]) | ((unsigned)f2h(acc_[3]) << 16);        \
      atomicAdd(&histP[lq * HSTR + ((pw_.x >> 9) & 0x7Fu)],                   \
                1u << (((pw_.x >> 8) & 1u) << 4));                            \
      atomicAdd(&histP[lq * HSTR + (pw_.x >> 25)],                            \
                1u << (((pw_.x >> 24) & 1u) << 4));                           \
      atomicAdd(&histP[lq * HSTR + ((pw_.y >> 9) & 0x7Fu)],                   \
                1u << (((pw_.y >> 8) & 1u) << 4));                            \
      atomicAdd(&histP[lq * HSTR + (pw_.y >> 25)],                            \
                1u << (((pw_.y >> 24) & 1u) << 4));                           \
      const int st_ = (w * 16 + (gg) * 4 + tt) * 16;                          \
      *(uint2*)&scH[lq * SROW + ((st_ + 4 * lg) ^ xr8q)] = pw_;               \
    }                                                                         \
  } while (0)

// One WG = 512 thr (8 waves) per (n, h, 16 q-rows). 76.6 KB LDS => 2 WG/CU,
// 16 waves/CU (4/SIMD). Two independent WGs interleave across barriers.
__global__ __launch_bounds__(512, 2) void sparse_attn(
    const ushort_t* __restrict__ Qf, const ushort_t* __restrict__ Kfp,
    const ushort_t* __restrict__ Vt, ushort_t* __restrict__ AOhi,
    ushort_t* __restrict__ AOlo) {
  __shared__ ushort_t scH[16 * SROW];   // 65536 B fp16 scores, then fp16 P
  __shared__ unsigned histP[16 * HSTR]; // 8448 B packed u16x2 counts (RAW bins)
  __shared__ float Obuf[16 * 68];       // 4352 B partial O [q][d]
  __shared__ float dinvS[16];

  // bijective XCD swizzle: each XCD owns a contiguous 512-block range
  const int flat = blockIdx.x + 128 * (blockIdx.y + 16 * blockIdx.z);
  const int idx = (flat & 7) * 512 + (flat >> 3);
  const int lb = idx & 127, h = (idx >> 7) & 15, n = idx >> 11;

  const int tid = threadIdx.x;
  const int lane = tid & 63, w = tid >> 6;  // w 0..7
  const int lg = lane >> 4, lq = lane & 15;
  const int xr8q = (lq & 7) << 3;
  const size_t nh = (size_t)(n * 16 + h);

  for (int i = tid; i < 16 * HSTR; i += 512) histP[i] = 0u;
  for (int i = tid; i < 16 * 68; i += 512) Obuf[i] = 0.f;

  // Q frags (fp16, pre-scaled incl. log2e): B-operand B[k=d][c=q=lq]
  const size_t qo = (nh * 2048 + (size_t)lb * 16 + lq) * 64 + lg * 8;
  const f16x8 qf0 = *(const f16x8*)&Qf[qo];
  const f16x8 qf1 = *(const f16x8*)&Qf[qo + 32];

  const ushort_t* Kf = Kfp + nh * 2048 * 64;
  const ushort_t* kbase = Kf + (size_t)(w * 256 + lq) * 64 + lg * 8;

  __syncthreads();  // hist + Obuf zeroed

  // ---------------- Phase 1: 16 s-tiles per wave ----------------
  {
    f16x8 fa[8], fb[8];
    KLOAD(fa, 0);
    for (int g = 0; g < 4; g += 2) {
      KLOAD(fb, g + 1);
      KCOMP(fa, g);
      if (g + 2 < 4) KLOAD(fa, g + 2);
      KCOMP(fb, g + 1);
    }
  }
  __syncthreads();  // scores + hist complete

  // ---------------- Phase 2: rows 2w, 2w+1 ----------------
  for (int rr = 0; rr < 2; rr++) {
    const int r = w * 2 + rr;
    const int rb = r * SROW;
    const int xr = (r & 7) << 3;
    unsigned* hrow = &histP[r * HSTR];

    int b1r; unsigned rem;
    scan_row<true>(hrow, KSEL, lane, &b1r, &rem);
    // rank bin -> raw top-8 bin; sub-byte rank xor (pos: desc, neg: asc)
    const unsigned rb1 = (b1r < 128) ? (unsigned)(b1r ^ 0x7F) : (unsigned)b1r;
    const unsigned sxor = (rb1 & 0x80u) ? 0u : 0xFFu;

    // read this lane's 32 scores ONCE
    uint4 rv0 = *(const uint4*)&scH[rb + ((0 * 512 + lane * 8) ^ xr)];
    uint4 rv1 = *(const uint4*)&scH[rb + ((1 * 512 + lane * 8) ^ xr)];
    uint4 rv2 = *(const uint4*)&scH[rb + ((2 * 512 + lane * 8) ^ xr)];
    uint4 rv3 = *(const uint4*)&scH[rb + ((3 * 512 + lane * 8) ^ xr)];

    // refine within raw bin rb1 (sub-bins stored rank-ordered), from regs
    *(uint2*)&hrow[lane << 1] = make_uint2(0u, 0u);
    __threadfence_block();
    auto refine1 = [&](unsigned wd) {
      if (((wd >> 8) & 0xFFu) == rb1) {
        unsigned sr_ = (wd & 0xFFu) ^ sxor;
        atomicAdd(&hrow[sr_ >> 1], 1u << ((sr_ & 1u) << 4));
      }
      if ((wd >> 24) == rb1) {
        unsigned sr_ = ((wd >> 16) & 0xFFu) ^ sxor;
        atomicAdd(&hrow[sr_ >> 1], 1u << ((sr_ & 1u) << 4));
      }
    };
    refine1(rv0.x); refine1(rv0.y); refine1(rv0.z); refine1(rv0.w);
    refine1(rv1.x); refine1(rv1.y); refine1(rv1.z); refine1(rv1.w);
    refine1(rv2.x); refine1(rv2.y); refine1(rv2.z); refine1(rv2.w);
    refine1(rv3.x); refine1(rv3.y); refine1(rv3.z); refine1(rv3.w);
    __threadfence_block();
    int b2r; unsigned rem2;
    scan_row<false>(hrow, rem, lane, &b2r, &rem2);
    (void)rem2;
    // exact fp16 threshold value: keep iff score >= fV
    const unsigned vbits = (rb1 << 8) | (((unsigned)b2r) ^ sxor);
    const float fV = h2f((ushort_t)vbits);

    // exp2 from registers (scores pre-scaled by log2e): fp16 P in place
    float den = 0.f;
    auto exp2w = [&](unsigned wd) -> unsigned {
      float f0 = h2f((ushort_t)(wd & 0xffffu));
      float f1 = h2f((ushort_t)(wd >> 16));
      float e0 = (f0 >= fV) ? __builtin_amdgcn_exp2f(f0) : 0.f;
      float e1 = (f1 >= fV) ? __builtin_amdgcn_exp2f(f1) : 0.f;
      den += e0 + e1;
      return (unsigned)f2h(e0) | ((unsigned)f2h(e1) << 16);
    };
    uint4 ov;
    ov.x = exp2w(rv0.x); ov.y = exp2w(rv0.y); ov.z = exp2w(rv0.z); ov.w = exp2w(rv0.w);
    *(uint4*)&scH[rb + ((0 * 512 + lane * 8) ^ xr)] = ov;
    ov.x = exp2w(rv1.x); ov.y = exp2w(rv1.y); ov.z = exp2w(rv1.z); ov.w = exp2w(rv1.w);
    *(uint4*)&scH[rb + ((1 * 512 + lane * 8) ^ xr)] = ov;
    ov.x = exp2w(rv2.x); ov.y = exp2w(rv2.y); ov.z = exp2w(rv2.z); ov.w = exp2w(rv2.w);
    *(uint4*)&scH[rb + ((2 * 512 + lane * 8) ^ xr)] = ov;
    ov.x = exp2w(rv3.x); ov.y = exp2w(rv3.y); ov.z = exp2w(rv3.z); ov.w = exp2w(rv3.w);
    *(uint4*)&scH[rb + ((3 * 512 + lane * 8) ^ xr)] = ov;

#pragma unroll
    for (int off = 32; off > 0; off >>= 1) den += __shfl_xor(den, off);
    if (lane == 0) dinvS[r] = 1.0f / den;
  }
  __syncthreads();  // P + dinvS ready

  // ---- Phase 3: PV quadrant (d-block w&3, s-half w>>2), 3-deep prefetch ----
  {
    const int db = w & 3, sh = w >> 2;
    const int sOff = sh * 1024;
    const ushort_t* Vb =
        Vt + (nh * 64 + (size_t)(db * 16 + lq)) * 2048 + sOff;
    const int xw = (lq & 7) << 3;
    const int arow = lq * SROW;
    f32x4 o0 = {0.f, 0.f, 0.f, 0.f}, o1 = o0, o2 = o0, o3 = o0;
    f16x8 va0 = *(const f16x8*)&Vb[lg * 8];
    f16x8 va1 = *(const f16x8*)&Vb[32 + lg * 8];
    f16x8 vb0 = *(const f16x8*)&Vb[64 + lg * 8];
    f16x8 vb1 = *(const f16x8*)&Vb[96 + lg * 8];
#pragma unroll 2
    for (int c = 0; c < 16; c += 2) {
      f16x8 na0, na1, nb0, nb1;
      if (c + 2 < 16) {
        na0 = *(const f16x8*)&Vb[(c + 2) * 64 + lg * 8];
        na1 = *(const f16x8*)&Vb[(c + 2) * 64 + 32 + lg * 8];
        nb0 = *(const f16x8*)&Vb[(c + 3) * 64 + lg * 8];
        nb1 = *(const f16x8*)&Vb[(c + 3) * 64 + 32 + lg * 8];
      }
      f16x8 pa0 = *(const f16x8*)&scH[arow + ((sOff + c * 64 + lg * 8) ^ xw)];
      f16x8 pa1 = *(const f16x8*)&scH[arow + ((sOff + c * 64 + 32 + lg * 8) ^ xw)];
      o0 = MFMAH16(pa0, va0, o0);
      o1 = MFMAH16(pa1, va1, o1);
      f16x8 pb0_ = *(const f16x8*)&scH[arow + ((sOff + (c + 1) * 64 + lg * 8) ^ xw)];
      f16x8 pb1_ = *(const f16x8*)&scH[arow + ((sOff + (c + 1) * 64 + 32 + lg * 8) ^ xw)];
      o2 = MFMAH16(pb0_, vb0, o2);
      o3 = MFMAH16(pb1_, vb1, o3);
      va0 = na0; va1 = na1; vb0 = nb0; vb1 = nb1;
    }
    f32x4 oa = (o0 + o1) + (o2 + o3);
#pragma unroll
    for (int ri = 0; ri < 4; ri++) {
      int q = lg * 4 + ri;
      atomicAdd(&Obuf[q * 68 + db * 16 + lq], oa[ri]);
    }
  }
  __syncthreads();  // partial O combined

  // ---- epilogue: scale by 1/den, write AO2[h][m][d] (line-dense) ----
  {
#pragma unroll
    for (int rep = 0; rep < 2; rep++) {
      int idx2 = tid + rep * 512;
      int q = idx2 >> 6, d = idx2 & 63;
      float val = Obuf[q * 68 + d] * dinvS[q];
      size_t ai = ((size_t)h * 4096 + (size_t)(lb * 16 + q) * 2 + n) * 64 +
                  (size_t)d;
      ushort_t hb = f2bf(val);
      AOhi[ai] = hb;
      AOlo[ai] = f2bf(val - bf2f(hb));
    }
  }
}

extern "C" void kernel_launch(void* const* d_in, const int* in_sizes, int n_in,
                              void* d_out, int out_size, void* d_ws, size_t ws_size,
                              hipStream_t stream) {
  const float* query = (const float*)d_in[0];
  const float* key   = (const float*)d_in[1];
  const float* value = (const float*)d_in[2];
  const float* Wq    = (const float*)d_in[3];
  const float* bq    = (const float*)d_in[4];
  const float* Wk    = (const float*)d_in[5];
  const float* bk    = (const float*)d_in[6];
  const float* Wv    = (const float*)d_in[7];
  const float* bv    = (const float*)d_in[8];
  const float* Wo    = (const float*)d_in[9];
  const float* bo    = (const float*)d_in[10];

  ushort_t* Qf   = (ushort_t*)d_ws;
  ushort_t* Kf   = Qf + 4194304;
  ushort_t* Vt   = Kf + 4194304;
  ushort_t* AOhi = Vt + 4194304;
  ushort_t* AOlo = AOhi + 4194304;
  ushort_t* Whi  = AOlo + 4194304;
  ushort_t* Wlo  = Whi + 4194304;

  dim3 block(256);
  presplit_w<<<dim3(512, 4), block, 0, stream>>>(Wq, Wk, Wv, Wo, Whi, Wlo);

  proj_qkv<<<dim3(8, 64, 3), block, 0, stream>>>(query, key, value, bq, bk, bv,
                                                 Whi, Qf, Kf, Vt);

  sparse_attn<<<dim3(128, 16, 2), dim3(512), 0, stream>>>(Qf, Kf, Vt, AOhi, AOlo);

  proj_out<<<dim3(8, 64), block, 0, stream>>>(AOhi, AOlo, Whi + 3 * 1048576,
                                              Wlo + 3 * 1048576, bo,
                                              (float*)d_out);
}

// Round 7
// 356.792 us; speedup vs baseline: 1.0726x; 1.0004x over previous
//
#include <hip/hip_runtime.h>
#include <hip/hip_bf16.h>
#include <hip/hip_fp16.h>

// MultiHeadSparseAttention. R24 = R23 with the Wo-presplit (m==3 slice of
// presplit_w: strided gather + bf16 hi/lo split, ~3-4us serial) moved into
// proj_qkv as grid slice z==3 (512 blocks = exact shape match). HIP
// dispatches z-last so these blocks fill proj_qkv's tail gap (1536 GEMM
// blocks / 1024 co-resident = half-empty 2nd batch) -> Wo prep rides free.
// presplit_w shrinks to (512,3). sparse_attn BYTE-EXACT R20 (268us; R21/R22
// proved any reordering costs ~25us). proj_out unchanged (R23 64x128).
//   P1: wave w -> 16 s-tiles (s in [w*256, w*256+256))
//   P2: wave w -> rows 2w, 2w+1 (scan + refine + exp pass, per-row)
//   P3: wave w -> (d-block w&3, s-half w>>2); f32-atomic combine in Obuf
// L=S=2048, N=2, E=1024, H=16, D=64, k_sel = int(2048*sigmoid(0.3)) = 1176.
//
// ws (halfwords): Qf 4M | Kf 4M | Vt 4M | AOhi 4M | AOlo 4M | Whi 4M | Wlo 4M

#define KSEL 1176u
#define SROW 2048  // fp16 score row stride (elements) — bank-aligned rows
#define HSTR 132   // hist row stride in u32

typedef __attribute__((ext_vector_type(8))) short bf16x8;
typedef __attribute__((ext_vector_type(8))) _Float16 f16x8;
typedef __attribute__((ext_vector_type(4))) float f32x4;
typedef unsigned short ushort_t;

union S8 { bf16x8 v; ushort_t u[8]; };
union H8 { f16x8 v; ushort_t u[8]; };

#define MFMA16(A, B, C)  __builtin_amdgcn_mfma_f32_16x16x32_bf16(A, B, C, 0, 0, 0)
#define MFMAH16(A, B, C) __builtin_amdgcn_mfma_f32_16x16x32_f16(A, B, C, 0, 0, 0)

__device__ __forceinline__ ushort_t f2bf(float x) {  // RNE f32->bf16
  unsigned u = __float_as_uint(x);
  return (ushort_t)((u + 0x7FFFu + ((u >> 16) & 1u)) >> 16);
}
__device__ __forceinline__ float bf2f(ushort_t b) {
  return __uint_as_float(((unsigned)b) << 16);
}
__device__ __forceinline__ ushort_t f2h(float x) {
  return __half_as_ushort(__float2half(x));
}
__device__ __forceinline__ float h2f(ushort_t b) {
  return __half2float(__ushort_as_half(b));
}

// convert 8 fp32 (two float4) to fp16, store as f16x8
__device__ __forceinline__ void cvt8(ushort_t* dst, float4 p, float4 q) {
  H8 t;
  t.u[0] = f2h(p.x); t.u[1] = f2h(p.y); t.u[2] = f2h(p.z); t.u[3] = f2h(p.w);
  t.u[4] = f2h(q.x); t.u[5] = f2h(q.y); t.u[6] = f2h(q.z); t.u[7] = f2h(q.w);
  *(f16x8*)dst = t.v;
}

// ---- W prep: Wq/Wk/Wv -> fp16 (Whi only); Wo handled inside proj_qkv ----
__global__ __launch_bounds__(256) void presplit_w(
    const float* __restrict__ W0, const float* __restrict__ W1,
    const float* __restrict__ W2, ushort_t* __restrict__ Whi) {
  const int m = blockIdx.y;
  const float* W = (m == 0) ? W0 : (m == 1) ? W1 : W2;
  const size_t off = ((size_t)blockIdx.x * 256 + threadIdx.x) * 8;
  const size_t base = (size_t)m * 1048576 + off;
  float4 p = *(const float4*)&W[off];
  float4 q = *(const float4*)&W[off + 4];
  cvt8(&Whi[base], p, q);
}

// -------- fused Q/K/V projection: 64x128 tile, plain fp16, 1 MFMA --------
// grid z==3 slice: Wo -> bf16 hi/lo PERMUTED presplit (rides the GEMM tail)
__global__ __launch_bounds__(256, 4) void proj_qkv(
    const float* __restrict__ Xq, const float* __restrict__ Xk,
    const float* __restrict__ Xv, const float* __restrict__ bq,
    const float* __restrict__ bk, const float* __restrict__ bv,
    const ushort_t* __restrict__ Whi, ushort_t* __restrict__ Qf,
    ushort_t* __restrict__ Kf, ushort_t* __restrict__ Vt,
    const float* __restrict__ Wo, ushort_t* __restrict__ WhiO,
    ushort_t* __restrict__ WloO) {
  __shared__ ushort_t Ah[64 * 72], Bh[128 * 72];
  const int z = blockIdx.z;
  if (z == 3) {  // Wo presplit: 512 blocks x 256 thr x 8 elems
    const int bid = blockIdx.x + 8 * blockIdx.y;
    const size_t off = ((size_t)bid * 256 + threadIdx.x) * 8;
    const int f = (int)(off >> 10);
    const int r = (int)(off & 1023);
    const int hcol = r >> 6, d0 = r & 63;
    S8 hi_, lo_;
#pragma unroll
    for (int j = 0; j < 8; j++) {
      float x = Wo[(size_t)f * 1024 + (size_t)(d0 + j) * 16 + hcol];
      ushort_t hb = f2bf(x);
      hi_.u[j] = hb;
      lo_.u[j] = f2bf(x - bf2f(hb));
    }
    *(bf16x8*)&WhiO[off] = hi_.v;
    *(bf16x8*)&WloO[off] = lo_.v;
    return;
  }
  const float* X = (z == 0) ? Xq : (z == 1) ? Xk : Xv;
  const float* bias = (z == 0) ? bq : (z == 1) ? bk : bv;
  const size_t zoff = (size_t)z * 1048576;

  const int tid = threadIdx.x;
  const int n0 = blockIdx.x * 128, m0 = blockIdx.y * 64;
  const int lane = tid & 63, wv = tid >> 6;
  const int lg = lane >> 4, lq = lane & 15;
  const int wr = wv >> 1, wc = wv & 1;
  const int sr = tid >> 2, c8 = (tid & 3) * 8;

  f32x4 acc[2][4] = {};

  const float* Xr = &X[(size_t)(m0 + sr) * 1024 + c8];
  const ushort_t* Bg0 = Whi + zoff + (size_t)(n0 + sr) * 1024 + c8;
  const ushort_t* Bg1 = Bg0 + 64 * 1024;

  float4 a0 = *(const float4*)&Xr[0],  a1 = *(const float4*)&Xr[4];
  float4 a2 = *(const float4*)&Xr[32], a3 = *(const float4*)&Xr[36];
  f16x8 pb0 = *(const f16x8*)&Bg0[0], pb1 = *(const f16x8*)&Bg0[32];
  f16x8 pb2 = *(const f16x8*)&Bg1[0], pb3 = *(const f16x8*)&Bg1[32];

  for (int k0 = 0; k0 < 1024; k0 += 64) {
    __syncthreads();
    cvt8(&Ah[sr * 72 + c8], a0, a1);
    cvt8(&Ah[sr * 72 + c8 + 32], a2, a3);
    *(f16x8*)&Bh[sr * 72 + c8] = pb0;
    *(f16x8*)&Bh[sr * 72 + c8 + 32] = pb1;
    *(f16x8*)&Bh[(64 + sr) * 72 + c8] = pb2;
    *(f16x8*)&Bh[(64 + sr) * 72 + c8 + 32] = pb3;
    if (k0 + 64 < 1024) {
      const float* Xn = Xr + k0 + 64;
      a0 = *(const float4*)&Xn[0];  a1 = *(const float4*)&Xn[4];
      a2 = *(const float4*)&Xn[32]; a3 = *(const float4*)&Xn[36];
      pb0 = *(const f16x8*)&Bg0[k0 + 64];
      pb1 = *(const f16x8*)&Bg0[k0 + 96];
      pb2 = *(const f16x8*)&Bg1[k0 + 64];
      pb3 = *(const f16x8*)&Bg1[k0 + 96];
    }
    __syncthreads();
#pragma unroll
    for (int kh = 0; kh < 2; kh++) {
      const int ko = kh * 32 + lg * 8;
      f16x8 bh0 = *(const f16x8*)&Bh[(wc * 64 + lq) * 72 + ko];
      f16x8 bh1 = *(const f16x8*)&Bh[(wc * 64 + 16 + lq) * 72 + ko];
      f16x8 bh2 = *(const f16x8*)&Bh[(wc * 64 + 32 + lq) * 72 + ko];
      f16x8 bh3 = *(const f16x8*)&Bh[(wc * 64 + 48 + lq) * 72 + ko];
#pragma unroll
      for (int i = 0; i < 2; i++) {
        f16x8 ahv = *(const f16x8*)&Ah[(wr * 32 + i * 16 + lq) * 72 + ko];
        acc[i][0] = MFMAH16(ahv, bh0, acc[i][0]);
        acc[i][1] = MFMAH16(ahv, bh1, acc[i][1]);
        acc[i][2] = MFMAH16(ahv, bh2, acc[i][2]);
        acc[i][3] = MFMAH16(ahv, bh3, acc[i][3]);
      }
    }
  }

  ushort_t* dqk = (z == 0) ? Qf : Kf;
#pragma unroll
  for (int i = 0; i < 2; i++)
#pragma unroll
    for (int j = 0; j < 4; j++)
#pragma unroll
      for (int ri = 0; ri < 4; ri++) {
        int m = m0 + wr * 32 + i * 16 + 4 * lg + ri;
        int e = n0 + wc * 64 + j * 16 + lq;
        float v = acc[i][j][ri] + bias[e];
        int l = m >> 1, n = m & 1, hh = e >> 6, d = e & 63;
        if (z == 2) {
          Vt[((size_t)(n * 16 + hh) * 64 + d) * 2048 + l] = f2h(v);
        } else {
          // Q scale = 1/sqrt(64) * log2(e): scores land in exp2 domain
          float x = (z == 0) ? v * (0.125f * 1.4426950408889634f) : v;
          dqk[((size_t)(n * 16 + hh) * 2048 + l) * 64 + d] = f2h(x);
        }
      }
}

// --- output projection: 64x128 tile; A = AO2[h][m][d] hi/lo, B = WoP ---
__global__ __launch_bounds__(256, 2) void proj_out(
    const ushort_t* __restrict__ AOhi, const ushort_t* __restrict__ AOlo,
    const ushort_t* __restrict__ Whi3, const ushort_t* __restrict__ Wlo3,
    const float* __restrict__ bias, float* __restrict__ out) {
  __shared__ ushort_t Ah[64 * 72], Al[64 * 72], Bh[128 * 72], Bl[128 * 72];
  const int tid = threadIdx.x;
  const int n0 = blockIdx.x * 128, m0 = blockIdx.y * 64;
  const int lane = tid & 63, wv = tid >> 6;
  const int lg = lane >> 4, lq = lane & 15;
  const int wr = wv >> 1, wc = wv & 1;
  const int sr = tid >> 2, c8 = (tid & 3) * 8;

  f32x4 acc[2][4] = {};

  const size_t abase = (size_t)(m0 + sr) * 64 + c8;
  const ushort_t* Bg0 = Whi3 + (size_t)(n0 + sr) * 1024 + c8;
  const ushort_t* Bg1 = Bg0 + 64 * 1024;
  const ushort_t* Lg0 = Wlo3 + (size_t)(n0 + sr) * 1024 + c8;
  const ushort_t* Lg1 = Lg0 + 64 * 1024;

  bf16x8 pa0 = *(const bf16x8*)&AOhi[abase], pa1 = *(const bf16x8*)&AOhi[abase + 32];
  bf16x8 pc0 = *(const bf16x8*)&AOlo[abase], pc1 = *(const bf16x8*)&AOlo[abase + 32];
  bf16x8 pb0 = *(const bf16x8*)&Bg0[0], pb1 = *(const bf16x8*)&Bg0[32];
  bf16x8 pb2 = *(const bf16x8*)&Bg1[0], pb3 = *(const bf16x8*)&Bg1[32];
  bf16x8 pl0 = *(const bf16x8*)&Lg0[0], pl1 = *(const bf16x8*)&Lg0[32];
  bf16x8 pl2 = *(const bf16x8*)&Lg1[0], pl3 = *(const bf16x8*)&Lg1[32];

  for (int k0 = 0; k0 < 1024; k0 += 64) {
    __syncthreads();
    *(bf16x8*)&Ah[sr * 72 + c8] = pa0;  *(bf16x8*)&Ah[sr * 72 + c8 + 32] = pa1;
    *(bf16x8*)&Al[sr * 72 + c8] = pc0;  *(bf16x8*)&Al[sr * 72 + c8 + 32] = pc1;
    *(bf16x8*)&Bh[sr * 72 + c8] = pb0;  *(bf16x8*)&Bh[sr * 72 + c8 + 32] = pb1;
    *(bf16x8*)&Bh[(64 + sr) * 72 + c8] = pb2;
    *(bf16x8*)&Bh[(64 + sr) * 72 + c8 + 32] = pb3;
    *(bf16x8*)&Bl[sr * 72 + c8] = pl0;  *(bf16x8*)&Bl[sr * 72 + c8 + 32] = pl1;
    *(bf16x8*)&Bl[(64 + sr) * 72 + c8] = pl2;
    *(bf16x8*)&Bl[(64 + sr) * 72 + c8 + 32] = pl3;
    if (k0 + 64 < 1024) {
      const size_t an = abase + (size_t)((k0 >> 6) + 1) * 262144;
      pa0 = *(const bf16x8*)&AOhi[an]; pa1 = *(const bf16x8*)&AOhi[an + 32];
      pc0 = *(const bf16x8*)&AOlo[an]; pc1 = *(const bf16x8*)&AOlo[an + 32];
      pb0 = *(const bf16x8*)&Bg0[k0 + 64]; pb1 = *(const bf16x8*)&Bg0[k0 + 96];
      pb2 = *(const bf16x8*)&Bg1[k0 + 64]; pb3 = *(const bf16x8*)&Bg1[k0 + 96];
      pl0 = *(const bf16x8*)&Lg0[k0 + 64]; pl1 = *(const bf16x8*)&Lg0[k0 + 96];
      pl2 = *(const bf16x8*)&Lg1[k0 + 64]; pl3 = *(const bf16x8*)&Lg1[k0 + 96];
    }
    __syncthreads();
#pragma unroll
    for (int kh = 0; kh < 2; kh++) {
      const int ko = kh * 32 + lg * 8;
#pragma unroll
      for (int i = 0; i < 2; i++) {
        bf16x8 ahv = *(const bf16x8*)&Ah[(wr * 32 + i * 16 + lq) * 72 + ko];
        bf16x8 alv = *(const bf16x8*)&Al[(wr * 32 + i * 16 + lq) * 72 + ko];
#pragma unroll
        for (int j = 0; j < 4; j++) {
          bf16x8 bhv = *(const bf16x8*)&Bh[(wc * 64 + j * 16 + lq) * 72 + ko];
          bf16x8 blv = *(const bf16x8*)&Bl[(wc * 64 + j * 16 + lq) * 72 + ko];
          acc[i][j] = MFMA16(ahv, bhv, acc[i][j]);
          acc[i][j] = MFMA16(alv, bhv, acc[i][j]);
          acc[i][j] = MFMA16(ahv, blv, acc[i][j]);
        }
      }
    }
  }

#pragma unroll
  for (int i = 0; i < 2; i++)
#pragma unroll
    for (int j = 0; j < 4; j++)
#pragma unroll
      for (int ri = 0; ri < 4; ri++) {
        int m = m0 + wr * 32 + i * 16 + 4 * lg + ri;
        int e = n0 + wc * 64 + j * 16 + lq;
        out[(size_t)m * 1024 + e] = acc[i][j][ri] + bias[e];
      }
}

// scan a packed-u16 256-bin hist row for the bin containing rank `target`.
// RANKMAP=true: hist is indexed by RAW fp16 top-8 bits; traverse in
// decreasing-VALUE order (raw 0x7F..0x00 then 0x80..0xFF). Output bin is a
// RANK in 0..255. RANKMAP=false: hist already rank-ordered.
template <bool RANKMAP>
__device__ __forceinline__ void scan_row(const unsigned* hrow, unsigned target,
                                         int lane, int* binOut, unsigned* remOut) {
  unsigned c0, c1, c2, c3;
  if (RANKMAP) {
    const bool neg = lane >= 32;
    const int ho = neg ? (lane << 1) : (62 - (lane << 1));
    uint2 hw = *(const uint2*)&hrow[ho];
    unsigned a0 = hw.x & 0xffffu, a1 = hw.x >> 16;
    unsigned a2 = hw.y & 0xffffu, a3 = hw.y >> 16;
    c0 = neg ? a0 : a3; c1 = neg ? a1 : a2;
    c2 = neg ? a2 : a1; c3 = neg ? a3 : a0;
  } else {
    uint2 hw = *(const uint2*)&hrow[lane << 1];
    c0 = hw.x & 0xffffu; c1 = hw.x >> 16;
    c2 = hw.y & 0xffffu; c3 = hw.y >> 16;
  }
  unsigned s4 = c0 + c1 + c2 + c3, incl = s4;
#pragma unroll
  for (int off = 1; off < 64; off <<= 1) {
    unsigned t = __shfl_up(incl, off);
    if (lane >= off) incl += t;
  }
  unsigned excl = incl - s4;
  bool found = (excl < target) && (target <= incl);
  int b = 0; unsigned rm = 1;
  if (found) {
    unsigned cum = excl;
    if (cum + c0 >= target) { b = (lane << 2); rm = target - cum; }
    else { cum += c0;
      if (cum + c1 >= target) { b = (lane << 2) + 1; rm = target - cum; }
      else { cum += c1;
        if (cum + c2 >= target) { b = (lane << 2) + 2; rm = target - cum; }
        else { cum += c2; b = (lane << 2) + 3; rm = target - cum; } } }
  }
  unsigned long long bal = __ballot(found);
  int src = (int)__builtin_ctzll(bal);
  *binOut = __shfl(b, src);
  *remOut = (unsigned)__shfl((int)rm, src);
}

// ---- P1 macros: fp16 K frag loads (per-lane base + const offsets) ----
#define KLOAD(F, gg)                                                   \
  do {                                                                 \
    _Pragma("unroll") for (int tt = 0; tt < 4; tt++) {                 \
      const int koff = ((gg) * 4 + tt) * 1024;                         \
      F[tt * 2 + 0] = *(const f16x8*)&kbase[koff];                     \
      F[tt * 2 + 1] = *(const f16x8*)&kbase[koff + 32];                \
    }                                                                  \
  } while (0)

// C = K·Q^T -> C[row=s_loc=4lg+ri][col=q=lq]; fp16 score + RAW top-8 hist
// (rank mapping deferred to P2's scan — no key math per score)
#define KCOMP(F, gg)                                                          \
  do {                                                                        \
    _Pragma("unroll") for (int tt = 0; tt < 4; tt++) {                        \
      f32x4 acc_ = {0.f, 0.f, 0.f, 0.f};                                      \
      acc_ = MFMAH16(F[tt * 2 + 0], qf0, acc_);                               \
      acc_ = MFMAH16(F[tt * 2 + 1], qf1, acc_);                               \
      uint2 pw_;                                                              \
      pw_.x = (unsigned)f2h(acc_[0]) | ((unsigned)f2h(acc_[1]) << 16);        \
      pw_.y = (unsigned)f2h(acc_[2]) | ((unsigned)f2h(acc_[3]) << 16);        \
      atomicAdd(&histP[lq * HSTR + ((pw_.x >> 9) & 0x7Fu)],                   \
                1u << (((pw_.x >> 8) & 1u) << 4));                            \
      atomicAdd(&histP[lq * HSTR + (pw_.x >> 25)],                            \
                1u << (((pw_.x >> 24) & 1u) << 4));                           \
      atomicAdd(&histP[lq * HSTR + ((pw_.y >> 9) & 0x7Fu)],                   \
                1u << (((pw_.y >> 8) & 1u) << 4));                            \
      atomicAdd(&histP[lq * HSTR + (pw_.y >> 25)],                            \
                1u << (((pw_.y >> 24) & 1u) << 4));                           \
      const int st_ = (w * 16 + (gg) * 4 + tt) * 16;                          \
      *(uint2*)&scH[lq * SROW + ((st_ + 4 * lg) ^ xr8q)] = pw_;               \
    }                                                                         \
  } while (0)

// One WG = 512 thr (8 waves) per (n, h, 16 q-rows). 76.6 KB LDS => 2 WG/CU,
// 16 waves/CU (4/SIMD). Two independent WGs interleave across barriers.
__global__ __launch_bounds__(512, 2) void sparse_attn(
    const ushort_t* __restrict__ Qf, const ushort_t* __restrict__ Kfp,
    const ushort_t* __restrict__ Vt, ushort_t* __restrict__ AOhi,
    ushort_t* __restrict__ AOlo) {
  __shared__ ushort_t scH[16 * SROW];   // 65536 B fp16 scores, then fp16 P
  __shared__ unsigned histP[16 * HSTR]; // 8448 B packed u16x2 counts (RAW bins)
  __shared__ float Obuf[16 * 68];       // 4352 B partial O [q][d]
  __shared__ float dinvS[16];

  // bijective XCD swizzle: each XCD owns a contiguous 512-block range
  const int flat = blockIdx.x + 128 * (blockIdx.y + 16 * blockIdx.z);
  const int idx = (flat & 7) * 512 + (flat >> 3);
  const int lb = idx & 127, h = (idx >> 7) & 15, n = idx >> 11;

  const int tid = threadIdx.x;
  const int lane = tid & 63, w = tid >> 6;  // w 0..7
  const int lg = lane >> 4, lq = lane & 15;
  const int xr8q = (lq & 7) << 3;
  const size_t nh = (size_t)(n * 16 + h);

  for (int i = tid; i < 16 * HSTR; i += 512) histP[i] = 0u;
  for (int i = tid; i < 16 * 68; i += 512) Obuf[i] = 0.f;

  // Q frags (fp16, pre-scaled incl. log2e): B-operand B[k=d][c=q=lq]
  const size_t qo = (nh * 2048 + (size_t)lb * 16 + lq) * 64 + lg * 8;
  const f16x8 qf0 = *(const f16x8*)&Qf[qo];
  const f16x8 qf1 = *(const f16x8*)&Qf[qo + 32];

  const ushort_t* Kf = Kfp + nh * 2048 * 64;
  const ushort_t* kbase = Kf + (size_t)(w * 256 + lq) * 64 + lg * 8;

  __syncthreads();  // hist + Obuf zeroed

  // ---------------- Phase 1: 16 s-tiles per wave ----------------
  {
    f16x8 fa[8], fb[8];
    KLOAD(fa, 0);
    for (int g = 0; g < 4; g += 2) {
      KLOAD(fb, g + 1);
      KCOMP(fa, g);
      if (g + 2 < 4) KLOAD(fa, g + 2);
      KCOMP(fb, g + 1);
    }
  }
  __syncthreads();  // scores + hist complete

  // ---------------- Phase 2: rows 2w, 2w+1 ----------------
  for (int rr = 0; rr < 2; rr++) {
    const int r = w * 2 + rr;
    const int rb = r * SROW;
    const int xr = (r & 7) << 3;
    unsigned* hrow = &histP[r * HSTR];

    int b1r; unsigned rem;
    scan_row<true>(hrow, KSEL, lane, &b1r, &rem);
    // rank bin -> raw top-8 bin; sub-byte rank xor (pos: desc, neg: asc)
    const unsigned rb1 = (b1r < 128) ? (unsigned)(b1r ^ 0x7F) : (unsigned)b1r;
    const unsigned sxor = (rb1 & 0x80u) ? 0u : 0xFFu;

    // read this lane's 32 scores ONCE
    uint4 rv0 = *(const uint4*)&scH[rb + ((0 * 512 + lane * 8) ^ xr)];
    uint4 rv1 = *(const uint4*)&scH[rb + ((1 * 512 + lane * 8) ^ xr)];
    uint4 rv2 = *(const uint4*)&scH[rb + ((2 * 512 + lane * 8) ^ xr)];
    uint4 rv3 = *(const uint4*)&scH[rb + ((3 * 512 + lane * 8) ^ xr)];

    // refine within raw bin rb1 (sub-bins stored rank-ordered), from regs
    *(uint2*)&hrow[lane << 1] = make_uint2(0u, 0u);
    __threadfence_block();
    auto refine1 = [&](unsigned wd) {
      if (((wd >> 8) & 0xFFu) == rb1) {
        unsigned sr_ = (wd & 0xFFu) ^ sxor;
        atomicAdd(&hrow[sr_ >> 1], 1u << ((sr_ & 1u) << 4));
      }
      if ((wd >> 24) == rb1) {
        unsigned sr_ = ((wd >> 16) & 0xFFu) ^ sxor;
        atomicAdd(&hrow[sr_ >> 1], 1u << ((sr_ & 1u) << 4));
      }
    };
    refine1(rv0.x); refine1(rv0.y); refine1(rv0.z); refine1(rv0.w);
    refine1(rv1.x); refine1(rv1.y); refine1(rv1.z); refine1(rv1.w);
    refine1(rv2.x); refine1(rv2.y); refine1(rv2.z); refine1(rv2.w);
    refine1(rv3.x); refine1(rv3.y); refine1(rv3.z); refine1(rv3.w);
    __threadfence_block();
    int b2r; unsigned rem2;
    scan_row<false>(hrow, rem, lane, &b2r, &rem2);
    (void)rem2;
    // exact fp16 threshold value: keep iff score >= fV
    const unsigned vbits = (rb1 << 8) | (((unsigned)b2r) ^ sxor);
    const float fV = h2f((ushort_t)vbits);

    // exp2 from registers (scores pre-scaled by log2e): fp16 P in place
    float den = 0.f;
    auto exp2w = [&](unsigned wd) -> unsigned {
      float f0 = h2f((ushort_t)(wd & 0xffffu));
      float f1 = h2f((ushort_t)(wd >> 16));
      float e0 = (f0 >= fV) ? __builtin_amdgcn_exp2f(f0) : 0.f;
      float e1 = (f1 >= fV) ? __builtin_amdgcn_exp2f(f1) : 0.f;
      den += e0 + e1;
      return (unsigned)f2h(e0) | ((unsigned)f2h(e1) << 16);
    };
    uint4 ov;
    ov.x = exp2w(rv0.x); ov.y = exp2w(rv0.y); ov.z = exp2w(rv0.z); ov.w = exp2w(rv0.w);
    *(uint4*)&scH[rb + ((0 * 512 + lane * 8) ^ xr)] = ov;
    ov.x = exp2w(rv1.x); ov.y = exp2w(rv1.y); ov.z = exp2w(rv1.z); ov.w = exp2w(rv1.w);
    *(uint4*)&scH[rb + ((1 * 512 + lane * 8) ^ xr)] = ov;
    ov.x = exp2w(rv2.x); ov.y = exp2w(rv2.y); ov.z = exp2w(rv2.z); ov.w = exp2w(rv2.w);
    *(uint4*)&scH[rb + ((2 * 512 + lane * 8) ^ xr)] = ov;
    ov.x = exp2w(rv3.x); ov.y = exp2w(rv3.y); ov.z = exp2w(rv3.z); ov.w = exp2w(rv3.w);
    *(uint4*)&scH[rb + ((3 * 512 + lane * 8) ^ xr)] = ov;

#pragma unroll
    for (int off = 32; off > 0; off >>= 1) den += __shfl_xor(den, off);
    if (lane == 0) dinvS[r] = 1.0f / den;
  }
  __syncthreads();  // P + dinvS ready

  // ---- Phase 3: PV quadrant (d-block w&3, s-half w>>2), 3-deep prefetch ----
  {
    const int db = w & 3, sh = w >> 2;
    const int sOff = sh * 1024;
    const ushort_t* Vb =
        Vt + (nh * 64 + (size_t)(db * 16 + lq)) * 2048 + sOff;
    const int xw = (lq & 7) << 3;
    const int arow = lq * SROW;
    f32x4 o0 = {0.f, 0.f, 0.f, 0.f}, o1 = o0, o2 = o0, o3 = o0;
    f16x8 va0 = *(const f16x8*)&Vb[lg * 8];
    f16x8 va1 = *(const f16x8*)&Vb[32 + lg * 8];
    f16x8 vb0 = *(const f16x8*)&Vb[64 + lg * 8];
    f16x8 vb1 = *(const f16x8*)&Vb[96 + lg * 8];
#pragma unroll 2
    for (int c = 0; c < 16; c += 2) {
      f16x8 na0, na1, nb0, nb1;
      if (c + 2 < 16) {
        na0 = *(const f16x8*)&Vb[(c + 2) * 64 + lg * 8];
        na1 = *(const f16x8*)&Vb[(c + 2) * 64 + 32 + lg * 8];
        nb0 = *(const f16x8*)&Vb[(c + 3) * 64 + lg * 8];
        nb1 = *(const f16x8*)&Vb[(c + 3) * 64 + 32 + lg * 8];
      }
      f16x8 pa0 = *(const f16x8*)&scH[arow + ((sOff + c * 64 + lg * 8) ^ xw)];
      f16x8 pa1 = *(const f16x8*)&scH[arow + ((sOff + c * 64 + 32 + lg * 8) ^ xw)];
      o0 = MFMAH16(pa0, va0, o0);
      o1 = MFMAH16(pa1, va1, o1);
      f16x8 pb0_ = *(const f16x8*)&scH[arow + ((sOff + (c + 1) * 64 + lg * 8) ^ xw)];
      f16x8 pb1_ = *(const f16x8*)&scH[arow + ((sOff + (c + 1) * 64 + 32 + lg * 8) ^ xw)];
      o2 = MFMAH16(pb0_, vb0, o2);
      o3 = MFMAH16(pb1_, vb1, o3);
      va0 = na0; va1 = na1; vb0 = nb0; vb1 = nb1;
    }
    f32x4 oa = (o0 + o1) + (o2 + o3);
#pragma unroll
    for (int ri = 0; ri < 4; ri++) {
      int q = lg * 4 + ri;
      atomicAdd(&Obuf[q * 68 + db * 16 + lq], oa[ri]);
    }
  }
  __syncthreads();  // partial O combined

  // ---- epilogue: scale by 1/den, write AO2[h][m][d] (line-dense) ----
  {
#pragma unroll
    for (int rep = 0; rep < 2; rep++) {
      int idx2 = tid + rep * 512;
      int q = idx2 >> 6, d = idx2 & 63;
      float val = Obuf[q * 68 + d] * dinvS[q];
      size_t ai = ((size_t)h * 4096 + (size_t)(lb * 16 + q) * 2 + n) * 64 +
                  (size_t)d;
      ushort_t hb = f2bf(val);
      AOhi[ai] = hb;
      AOlo[ai] = f2bf(val - bf2f(hb));
    }
  }
}

extern "C" void kernel_launch(void* const* d_in, const int* in_sizes, int n_in,
                              void* d_out, int out_size, void* d_ws, size_t ws_size,
                              hipStream_t stream) {
  const float* query = (const float*)d_in[0];
  const float* key   = (const float*)d_in[1];
  const float* value = (const float*)d_in[2];
  const float* Wq    = (const float*)d_in[3];
  const float* bq    = (const float*)d_in[4];
  const float* Wk    = (const float*)d_in[5];
  const float* bk    = (const float*)d_in[6];
  const float* Wv    = (const float*)d_in[7];
  const float* bv    = (const float*)d_in[8];
  const float* Wo    = (const float*)d_in[9];
  const float* bo    = (const float*)d_in[10];

  ushort_t* Qf   = (ushort_t*)d_ws;
  ushort_t* Kf   = Qf + 4194304;
  ushort_t* Vt   = Kf + 4194304;
  ushort_t* AOhi = Vt + 4194304;
  ushort_t* AOlo = AOhi + 4194304;
  ushort_t* Whi  = AOlo + 4194304;
  ushort_t* Wlo  = Whi + 4194304;

  dim3 block(256);
  presplit_w<<<dim3(512, 3), block, 0, stream>>>(Wq, Wk, Wv, Whi);

  proj_qkv<<<dim3(8, 64, 4), block, 0, stream>>>(query, key, value, bq, bk, bv,
                                                 Whi, Qf, Kf, Vt, Wo,
                                                 Whi + 3 * 1048576,
                                                 Wlo + 3 * 1048576);

  sparse_attn<<<dim3(128, 16, 2), dim3(512), 0, stream>>>(Qf, Kf, Vt, AOhi, AOlo);

  proj_out<<<dim3(8, 64), block, 0, stream>>>(AOhi, AOlo, Whi + 3 * 1048576,
                                              Wlo + 3 * 1048576, bo,
                                              (float*)d_out);
}